// Round 2
// baseline (1831.511 us; speedup 1.0000x reference)
//
#include <hip/hip_runtime.h>
#include <math.h>

#define NN 50000
#define EE 800000
#define FIN 128
#define HIDN 128
#define HD 32
#define FEATD 268
#define TE 32
#define TN 32

__device__ __forceinline__ float silu_f(float x) {
    return x / (1.0f + __expf(-x));
}

__global__ __launch_bounds__(256) void edge_kernel(
    const float* __restrict__ h, const float* __restrict__ coord,
    const int* __restrict__ ei,
    const float* __restrict__ eW1, const float* __restrict__ eb1,
    const float* __restrict__ eW2, const float* __restrict__ eb2,
    const float* __restrict__ ln_g, const float* __restrict__ ln_b,
    const float* __restrict__ cW1, const float* __restrict__ cb1,
    const float* __restrict__ cW2,
    float* __restrict__ agg, float* __restrict__ coord_out)
{
    __shared__ __align__(16) float smemA[FEATD * TE];   // feats [268][32]; later hid [32][132]
    __shared__ __align__(16) float efs[TE][HIDN + 4];   // edge_feat [32][132]
    __shared__ float cdiff[TE][3];
    __shared__ int   rowlds[TE];
    __shared__ float wred[4][16];

    float (*feats)[TE]      = reinterpret_cast<float (*)[TE]>(smemA);
    float (*hid)[HIDN + 4]  = reinterpret_cast<float (*)[HIDN + 4]>(smemA);

    const int t  = threadIdx.x;
    const int e0 = blockIdx.x * TE;

    // ---------------- Phase 0: gather h + geometry into feats ----------------
    {
        const int e = t >> 3;
        const int q = t & 7;
        const int r = ei[e0 + e];
        const int c = ei[EE + e0 + e];
        const float4* hr = reinterpret_cast<const float4*>(h + (size_t)r * FIN);
        const float4* hc = reinterpret_cast<const float4*>(h + (size_t)c * FIN);
        #pragma unroll
        for (int j = 0; j < 4; j++) {
            const int f4 = q + 8 * j;
            float4 v = hr[f4];
            feats[f4*4+0][e] = v.x; feats[f4*4+1][e] = v.y;
            feats[f4*4+2][e] = v.z; feats[f4*4+3][e] = v.w;
            float4 u = hc[f4];
            feats[FIN+f4*4+0][e] = u.x; feats[FIN+f4*4+1][e] = u.y;
            feats[FIN+f4*4+2][e] = u.z; feats[FIN+f4*4+3][e] = u.w;
        }
        if (q == 0) {
            rowlds[e] = r;
            const float cix = coord[(size_t)r*3+0], ciy = coord[(size_t)r*3+1], ciz = coord[(size_t)r*3+2];
            const float ckx = coord[(size_t)c*3+0], cky = coord[(size_t)c*3+1], ckz = coord[(size_t)c*3+2];
            const float dx = cix-ckx, dy = ciy-cky, dz = ciz-ckz;
            cdiff[e][0]=dx; cdiff[e][1]=dy; cdiff[e][2]=dz;
            const float radial = dx*dx + dy*dy + dz*dz;
            const float dist   = sqrtf(radial);
            const float dotv   = cix*ckx + ciy*cky + ciz*ckz;
            const float ia = 1.0f / (dist + 1e-8f);
            float ax = dx*ia, ay = dy*ia, az = dz*ia;
            const float cpx = ciy*ckz - ciz*cky;
            const float cpy = ciz*ckx - cix*ckz;
            const float cpz = cix*cky - ciy*ckx;
            const float cpn = sqrtf(cpx*cpx + cpy*cpy + cpz*cpz);
            const float ib = 1.0f / (cpn + 1e-8f);
            float bx = cpx*ib, by = cpy*ib, bz = cpz*ib;
            float cx = ay*bz - az*by;
            float cy = az*bx - ax*bz;
            float cz = ax*by - ay*bx;
            const float na = sqrtf(ax*ax + ay*ay + az*az);
            const float nb = sqrtf(bx*bx + by*by + bz*bz);
            const float nc = sqrtf(cx*cx + cy*cy + cz*cz);
            if (na < 1e-6f || nb < 1e-6f || nc < 1e-6f) {
                ax=1.f; bx=0.f; cx=0.f;
                ay=0.f; by=1.f; cy=0.f;
                az=0.f; bz=0.f; cz=1.f;
            }
            feats[256][e]=radial; feats[257][e]=dist; feats[258][e]=dotv;
            feats[259][e]=ax; feats[260][e]=bx; feats[261][e]=cx;
            feats[262][e]=ay; feats[263][e]=by; feats[264][e]=cy;
            feats[265][e]=az; feats[266][e]=bz; feats[267][e]=cz;
        }
    }
    __syncthreads();

    const int o  = t & 127;           // output feature 0..127
    const int g  = t >> 7;            // edge-half 0/1
    const int eb = g * 16;
    const int hh = o >> 5;            // head
    const int dd = o & 31;

    // ---------------- GEMM1: feats[268] -> 128 (per-head dense) ----------------
    float acc[16];
    #pragma unroll
    for (int i = 0; i < 16; i++) acc[i] = 0.f;
    {
        const float* W1 = eW1 + (size_t)hh * (FEATD * HD) + dd;
        #pragma unroll 4
        for (int f = 0; f < FEATD; f++) {
            const float w = W1[(size_t)f * HD];
            const float4* fr = reinterpret_cast<const float4*>(&feats[f][eb]);
            #pragma unroll
            for (int c4 = 0; c4 < 4; c4++) {
                float4 v = fr[c4];
                acc[4*c4+0] = fmaf(v.x, w, acc[4*c4+0]);
                acc[4*c4+1] = fmaf(v.y, w, acc[4*c4+1]);
                acc[4*c4+2] = fmaf(v.z, w, acc[4*c4+2]);
                acc[4*c4+3] = fmaf(v.w, w, acc[4*c4+3]);
            }
        }
    }
    __syncthreads();                  // done reading feats (aliased by hid)
    {
        const float b1 = eb1[o];
        #pragma unroll
        for (int e = 0; e < 16; e++)
            hid[eb+e][o] = silu_f(acc[e] + b1);
    }
    __syncthreads();

    // ---------------- GEMM2: block-diagonal 32x32 per head, + bias ----------------
    {
        float acc2[16];
        #pragma unroll
        for (int i = 0; i < 16; i++) acc2[i] = 0.f;
        const float* W2 = eW2 + (size_t)hh * (HD * HD) + dd;
        for (int k = 0; k < HD; k++) {
            const float w = W2[(size_t)k * HD];
            #pragma unroll
            for (int e = 0; e < 16; e++)
                acc2[e] = fmaf(hid[eb+e][hh*HD + k], w, acc2[e]);
        }
        const float b2 = eb2[o];
        #pragma unroll
        for (int e = 0; e < 16; e++)
            efs[eb+e][o] = acc2[e] + b2;
    }
    __syncthreads();

    // ---------------- LayerNorm over 128 ----------------
    {
        const int el = t >> 3;
        const int q  = t & 7;
        float s = 0.f, s2 = 0.f;
        #pragma unroll
        for (int i = 0; i < 16; i++) {
            const float v = efs[el][q*16 + i];
            s += v; s2 += v*v;
        }
        #pragma unroll
        for (int d = 1; d < 8; d <<= 1) { s += __shfl_xor(s, d); s2 += __shfl_xor(s2, d); }
        const float mu   = s * (1.f/128.f);
        const float var  = s2 * (1.f/128.f) - mu*mu;
        const float rstd = rsqrtf(var + 1e-5f);
        #pragma unroll
        for (int i = 0; i < 16; i++) {
            const int oo = q*16 + i;
            const float v = efs[el][oo];
            efs[el][oo] = (v - mu) * rstd * ln_g[oo] + ln_b[oo];
        }
    }
    __syncthreads();

    // ---------------- coord MLP: GEMM3 + reduce to w ----------------
    {
        float acc3[16];
        #pragma unroll
        for (int i = 0; i < 16; i++) acc3[i] = 0.f;
        for (int k = 0; k < HIDN; k++) {
            const float w = cW1[(size_t)k * HIDN + o];
            #pragma unroll
            for (int e = 0; e < 16; e++)
                acc3[e] = fmaf(efs[eb+e][k], w, acc3[e]);
        }
        const float cb = cb1[o];
        const float c2 = cW2[o];
        float p[16];
        #pragma unroll
        for (int e = 0; e < 16; e++) p[e] = silu_f(acc3[e] + cb) * c2;
        #pragma unroll
        for (int d = 1; d < 64; d <<= 1) {
            #pragma unroll
            for (int e = 0; e < 16; e++) p[e] += __shfl_xor(p[e], d);
        }
        const int lane = t & 63;
        const int wv   = t >> 6;
        float sel = p[0];
        #pragma unroll
        for (int i = 1; i < 16; i++) sel = ((lane & 15) == i) ? p[i] : sel;
        if (lane < 16) wred[wv][lane] = sel;
    }
    __syncthreads();

    if (t < TE) {
        const int e = t;
        const int base = (e >> 4) * 2;
        const float we = wred[base][e & 15] + wred[base+1][e & 15];
        const int r = rowlds[e];
        atomicAdd(&coord_out[(size_t)r*3+0], cdiff[e][0]*we);
        atomicAdd(&coord_out[(size_t)r*3+1], cdiff[e][1]*we);
        atomicAdd(&coord_out[(size_t)r*3+2], cdiff[e][2]*we);
    }

    // ---------------- agg scatter ----------------
    #pragma unroll
    for (int e = 0; e < 16; e++) {
        const int ee = eb + e;
        atomicAdd(&agg[(size_t)rowlds[ee]*HIDN + o], efs[ee][o]);
    }
}

__global__ __launch_bounds__(256) void node_kernel(
    const float* __restrict__ h, const float* __restrict__ agg,
    const float* __restrict__ nW1, const float* __restrict__ nb1,
    const float* __restrict__ nW2, const float* __restrict__ nb2,
    float* __restrict__ h_out)
{
    __shared__ __align__(16) float xs[2*FIN][TN];       // [256][32]
    __shared__ __align__(16) float hid[TN][HIDN + 4];   // [32][132]

    const int t  = threadIdx.x;
    const int n0 = blockIdx.x * TN;

    {
        const int n = t >> 3;
        const int q = t & 7;
        const int nid = n0 + n;
        const bool ok = nid < NN;
        const float4* hr = reinterpret_cast<const float4*>(h + (size_t)nid * FIN);
        const float4* ar = reinterpret_cast<const float4*>(agg + (size_t)nid * FIN);
        #pragma unroll
        for (int j = 0; j < 4; j++) {
            const int f4 = q + 8*j;
            float4 v = ok ? hr[f4] : make_float4(0.f,0.f,0.f,0.f);
            xs[f4*4+0][n]=v.x; xs[f4*4+1][n]=v.y; xs[f4*4+2][n]=v.z; xs[f4*4+3][n]=v.w;
            float4 u = ok ? ar[f4] : make_float4(0.f,0.f,0.f,0.f);
            xs[FIN+f4*4+0][n]=u.x; xs[FIN+f4*4+1][n]=u.y; xs[FIN+f4*4+2][n]=u.z; xs[FIN+f4*4+3][n]=u.w;
        }
    }
    __syncthreads();

    const int o   = t & 127;
    const int g   = t >> 7;
    const int nb_ = g * 16;

    float acc[16];
    #pragma unroll
    for (int i = 0; i < 16; i++) acc[i] = 0.f;
    #pragma unroll 4
    for (int k = 0; k < 2*FIN; k++) {
        const float w = nW1[(size_t)k * HIDN + o];
        const float4* fr = reinterpret_cast<const float4*>(&xs[k][nb_]);
        #pragma unroll
        for (int c4 = 0; c4 < 4; c4++) {
            float4 v = fr[c4];
            acc[4*c4+0] = fmaf(v.x, w, acc[4*c4+0]);
            acc[4*c4+1] = fmaf(v.y, w, acc[4*c4+1]);
            acc[4*c4+2] = fmaf(v.z, w, acc[4*c4+2]);
            acc[4*c4+3] = fmaf(v.w, w, acc[4*c4+3]);
        }
    }
    {
        const float b1 = nb1[o];
        #pragma unroll
        for (int e = 0; e < 16; e++)
            hid[nb_+e][o] = silu_f(acc[e] + b1);
    }
    __syncthreads();

    float acc2[16];
    #pragma unroll
    for (int i = 0; i < 16; i++) acc2[i] = 0.f;
    for (int k = 0; k < HIDN; k++) {
        const float w = nW2[(size_t)k * FIN + o];
        #pragma unroll
        for (int e = 0; e < 16; e++)
            acc2[e] = fmaf(hid[nb_+e][k], w, acc2[e]);
    }
    const float b2 = nb2[o];
    #pragma unroll
    for (int e = 0; e < 16; e++) {
        const int nid = n0 + nb_ + e;
        if (nid < NN)
            h_out[(size_t)nid*FIN + o] = h[(size_t)nid*FIN + o] + acc2[e] + b2;
    }
}

extern "C" void kernel_launch(void* const* d_in, const int* in_sizes, int n_in,
                              void* d_out, int out_size, void* d_ws, size_t ws_size,
                              hipStream_t stream)
{
    (void)in_sizes; (void)n_in; (void)out_size; (void)d_ws; (void)ws_size;
    const float* h     = (const float*)d_in[0];
    const float* coord = (const float*)d_in[1];
    const int*   ei    = (const int*)d_in[2];
    const float* eW1   = (const float*)d_in[3];
    const float* eb1   = (const float*)d_in[4];
    const float* eW2   = (const float*)d_in[5];
    const float* eb2   = (const float*)d_in[6];
    const float* ln_g  = (const float*)d_in[7];
    const float* ln_b  = (const float*)d_in[8];
    const float* nW1   = (const float*)d_in[9];
    const float* nb1   = (const float*)d_in[10];
    const float* nW2   = (const float*)d_in[11];
    const float* nb2   = (const float*)d_in[12];
    const float* cW1   = (const float*)d_in[13];
    const float* cb1   = (const float*)d_in[14];
    const float* cW2   = (const float*)d_in[15];

    float* h_out     = (float*)d_out;
    float* coord_out = h_out + (size_t)NN * FIN;
    // Use the h_out region of d_out as the agg accumulator (same size/shape as
    // agg [N,128] f32): zero it, scatter into it, node_kernel stages it into
    // LDS per-tile before overwriting with the final h_out. No ws needed.
    float* agg = h_out;

    hipMemsetAsync(agg, 0, (size_t)NN * HIDN * sizeof(float), stream);
    hipMemcpyAsync(coord_out, coord, (size_t)NN * 3 * sizeof(float),
                   hipMemcpyDeviceToDevice, stream);

    edge_kernel<<<EE/TE, 256, 0, stream>>>(h, coord, ei, eW1, eb1, eW2, eb2,
                                           ln_g, ln_b, cW1, cb1, cW2,
                                           agg, coord_out);
    node_kernel<<<(NN + TN - 1)/TN, 256, 0, stream>>>(h, agg, nW1, nb1, nW2, nb2, h_out);
}

// Round 6
// 686.810 us; speedup vs baseline: 2.6667x; 2.6667x over previous
//
#include <hip/hip_runtime.h>
#include <math.h>

#define NN 50000
#define EE 800000
#define FIN 128
#define HIDN 128
#define HD 32
#define FEATD 268
#define K1 288           // GEMM1 K padded to 9*32
#define KP1 296          // featsB LDS row stride (bf16 elems)
#define TE 64
#define TN 32

typedef __bf16 bf16x8 __attribute__((ext_vector_type(8)));
typedef __bf16 bf16x4 __attribute__((ext_vector_type(4)));
typedef float  f32x4  __attribute__((ext_vector_type(4)));

#define MFMA(a, b, c) __builtin_amdgcn_mfma_f32_16x16x32_bf16((a), (b), (c), 0, 0, 0)

__device__ __forceinline__ float silu_f(float x) {
    return x / (1.0f + __expf(-x));
}

// Transpose + bf16-convert weights into ws each launch (deterministic, ~5us).
// eW1t: [4][32][288] (row=out d, col=k, k>=268 zero)   from eW1 [4][268][32]
// eW2t: [4][32][32]  (row=out d, col=k)                 from eW2 [4][32][32]
// cW1t: [128][128]   (row=out,  col=k)                  from cW1 [128][128]
__global__ void wconv_kernel(const float* __restrict__ eW1, const float* __restrict__ eW2,
                             const float* __restrict__ cW1,
                             __bf16* __restrict__ eW1t, __bf16* __restrict__ eW2t,
                             __bf16* __restrict__ cW1t)
{
    const int i = blockIdx.x * 256 + threadIdx.x;
    if (i < 4 * 32 * K1) {
        const int hh = i / (32 * K1), rs = i % (32 * K1), d = rs / K1, k = rs % K1;
        const float v = (k < FEATD) ? eW1[(size_t)hh * FEATD * HD + (size_t)k * HD + d] : 0.f;
        eW1t[i] = (__bf16)v;
    }
    if (i < 4 * HD * HD) {
        const int hh = i / (HD * HD), rs = i % (HD * HD), d = rs / HD, k = rs % HD;
        eW2t[i] = (__bf16)eW2[(size_t)hh * HD * HD + (size_t)k * HD + d];
    }
    if (i < HIDN * HIDN) {
        const int o = i / HIDN, k = i % HIDN;
        cW1t[i] = (__bf16)cW1[(size_t)k * HIDN + o];
    }
}

__global__ __launch_bounds__(256) void edge_kernel(
    const float* __restrict__ h, const float* __restrict__ coord,
    const int* __restrict__ ei,
    const __bf16* __restrict__ eW1t, const float* __restrict__ eb1,
    const __bf16* __restrict__ eW2t, const float* __restrict__ eb2,
    const float* __restrict__ ln_g, const float* __restrict__ ln_b,
    const __bf16* __restrict__ cW1t, const float* __restrict__ cb1,
    const float* __restrict__ cW2,
    float* __restrict__ agg, float* __restrict__ coord_out)
{
    // Region A: featsB bf16[64][296] (37,888B) -> later efs f32[64][132] (33,792B)
    // Region B: hidB  bf16[4][64][40] (20,480B) -> later efsB bf16[64][136] (17,408B)
    __shared__ __align__(16) unsigned char smemA[TE * KP1 * 2];
    __shared__ __align__(16) unsigned char smemB[4 * TE * 40 * 2];
    __shared__ float cdiff[TE][3];
    __shared__ int   rowlds[TE];
    __shared__ float wsum[TE];

    __bf16 (*featsB)[KP1] = (__bf16 (*)[KP1])smemA;
    float  (*efs)[132]    = (float  (*)[132])smemA;
    __bf16 (*efsB)[136]   = (__bf16 (*)[136])smemB;

    const int t  = threadIdx.x;
    const int e0 = blockIdx.x * TE;

    if (t < TE) wsum[t] = 0.f;

    // ---------------- Phase 0: gather h (bf16) + geometry into featsB ----------------
    {
        const int e = t >> 2;        // edge 0..63
        const int q = t & 3;
        const int r = ei[e0 + e];
        const int c = ei[EE + e0 + e];
        const float4* hr = (const float4*)(h + (size_t)r * FIN);
        const float4* hc = (const float4*)(h + (size_t)c * FIN);
        #pragma unroll
        for (int j = 0; j < 8; j++) {
            const int f4 = q + 4 * j;
            float4 v = hr[f4];
            bf16x4 bv = { (__bf16)v.x, (__bf16)v.y, (__bf16)v.z, (__bf16)v.w };
            *(bf16x4*)&featsB[e][f4 * 4] = bv;
            float4 u = hc[f4];
            bf16x4 bu = { (__bf16)u.x, (__bf16)u.y, (__bf16)u.z, (__bf16)u.w };
            *(bf16x4*)&featsB[e][FIN + f4 * 4] = bu;
        }
        if (q == 0) {
            rowlds[e] = r;
            const float cix = coord[(size_t)r*3+0], ciy = coord[(size_t)r*3+1], ciz = coord[(size_t)r*3+2];
            const float ckx = coord[(size_t)c*3+0], cky = coord[(size_t)c*3+1], ckz = coord[(size_t)c*3+2];
            const float dx = cix-ckx, dy = ciy-cky, dz = ciz-ckz;
            cdiff[e][0]=dx; cdiff[e][1]=dy; cdiff[e][2]=dz;
            const float radial = dx*dx + dy*dy + dz*dz;
            const float dist   = sqrtf(radial);
            const float dotv   = cix*ckx + ciy*cky + ciz*ckz;
            const float ia = 1.0f / (dist + 1e-8f);
            float ax = dx*ia, ay = dy*ia, az = dz*ia;
            const float cpx = ciy*ckz - ciz*cky;
            const float cpy = ciz*ckx - cix*ckz;
            const float cpz = cix*cky - ciy*ckx;
            const float cpn = sqrtf(cpx*cpx + cpy*cpy + cpz*cpz);
            const float ib = 1.0f / (cpn + 1e-8f);
            float bx = cpx*ib, by = cpy*ib, bz = cpz*ib;
            float cx = ay*bz - az*by;
            float cy = az*bx - ax*bz;
            float cz = ax*by - ay*bx;
            const float na = sqrtf(ax*ax + ay*ay + az*az);
            const float nb = sqrtf(bx*bx + by*by + bz*bz);
            const float nc = sqrtf(cx*cx + cy*cy + cz*cz);
            if (na < 1e-6f || nb < 1e-6f || nc < 1e-6f) {
                ax=1.f; bx=0.f; cx=0.f;
                ay=0.f; by=1.f; cy=0.f;
                az=0.f; bz=0.f; cz=1.f;
            }
            featsB[e][256]=(__bf16)radial; featsB[e][257]=(__bf16)dist; featsB[e][258]=(__bf16)dotv;
            featsB[e][259]=(__bf16)ax; featsB[e][260]=(__bf16)bx; featsB[e][261]=(__bf16)cx;
            featsB[e][262]=(__bf16)ay; featsB[e][263]=(__bf16)by; featsB[e][264]=(__bf16)cy;
            featsB[e][265]=(__bf16)az; featsB[e][266]=(__bf16)bz; featsB[e][267]=(__bf16)cz;
            #pragma unroll
            for (int k = FEATD; k < K1; k++) featsB[e][k] = (__bf16)0.f;
        }
    }
    __syncthreads();

    const int wv   = t >> 6;          // wave id; = head for GEMM1/2, col-group for GEMM3
    const int lane = t & 63;
    const int lr   = lane & 15;       // fragment row/col index
    const int lg   = lane >> 4;       // k-group (0..3)

    __bf16* hidB = ((__bf16*)smemB) + wv * (TE * 40);

    const f32x4 z4 = { 0.f, 0.f, 0.f, 0.f };

    // ---------------- GEMM1 (MFMA): feats[64x288] @ eW1t^T -> hid[64x32] per head ----------------
    {
        f32x4 acc[4][2];
        #pragma unroll
        for (int mt = 0; mt < 4; mt++) { acc[mt][0] = z4; acc[mt][1] = z4; }
        const __bf16* W1 = eW1t + (size_t)wv * 32 * K1;
        #pragma unroll
        for (int ks = 0; ks < 9; ks++) {
            const int kof = ks * 32 + lg * 8;
            bf16x8 b0 = *(const bf16x8*)(W1 + (size_t)lr * K1 + kof);
            bf16x8 b1 = *(const bf16x8*)(W1 + (size_t)(16 + lr) * K1 + kof);
            #pragma unroll
            for (int mt = 0; mt < 4; mt++) {
                bf16x8 a = *(const bf16x8*)(&featsB[mt * 16 + lr][kof]);
                acc[mt][0] = MFMA(a, b0, acc[mt][0]);
                acc[mt][1] = MFMA(a, b1, acc[mt][1]);
            }
        }
        const float b1a = eb1[wv * HD + lr];
        const float b1b = eb1[wv * HD + 16 + lr];
        #pragma unroll
        for (int mt = 0; mt < 4; mt++) {
            #pragma unroll
            for (int r = 0; r < 4; r++) {
                const int erow = mt * 16 + lg * 4 + r;
                hidB[erow * 40 + lr]      = (__bf16)silu_f(acc[mt][0][r] + b1a);
                hidB[erow * 40 + 16 + lr] = (__bf16)silu_f(acc[mt][1][r] + b1b);
            }
        }
    }
    __syncthreads();

    // ---------------- GEMM2 (MFMA): hid[64x32] @ eW2t^T + b2 -> efs (fp32) ----------------
    {
        f32x4 acc2[4][2];
        #pragma unroll
        for (int mt = 0; mt < 4; mt++) { acc2[mt][0] = z4; acc2[mt][1] = z4; }
        const __bf16* W2 = eW2t + (size_t)wv * HD * HD;
        const int kof2 = lg * 8;
        bf16x8 b20 = *(const bf16x8*)(W2 + (size_t)lr * HD + kof2);
        bf16x8 b21 = *(const bf16x8*)(W2 + (size_t)(16 + lr) * HD + kof2);
        #pragma unroll
        for (int mt = 0; mt < 4; mt++) {
            bf16x8 a = *(const bf16x8*)(hidB + (mt * 16 + lr) * 40 + kof2);
            acc2[mt][0] = MFMA(a, b20, acc2[mt][0]);
            acc2[mt][1] = MFMA(a, b21, acc2[mt][1]);
        }
        const float b2a = eb2[wv * HD + lr];
        const float b2b = eb2[wv * HD + 16 + lr];
        #pragma unroll
        for (int mt = 0; mt < 4; mt++) {
            #pragma unroll
            for (int r = 0; r < 4; r++) {
                const int erow = mt * 16 + lg * 4 + r;
                efs[erow][wv * HD + lr]      = acc2[mt][0][r] + b2a;
                efs[erow][wv * HD + 16 + lr] = acc2[mt][1][r] + b2b;
            }
        }
    }
    __syncthreads();

    // ---------------- LayerNorm over 128 (fp32 in efs; bf16 copy to efsB) ----------------
    {
        const int el = t >> 2;
        const int q  = t & 3;
        float s = 0.f, s2 = 0.f;
        #pragma unroll
        for (int i = 0; i < 32; i++) {
            const float v = efs[el][q + 4 * i];
            s += v; s2 += v * v;
        }
        s  += __shfl_xor(s, 1);  s  += __shfl_xor(s, 2);
        s2 += __shfl_xor(s2, 1); s2 += __shfl_xor(s2, 2);
        const float mu   = s * (1.f / 128.f);
        const float var  = s2 * (1.f / 128.f) - mu * mu;
        const float rstd = rsqrtf(var + 1e-5f);
        #pragma unroll
        for (int i = 0; i < 32; i++) {
            const int oo = q + 4 * i;
            const float v  = efs[el][oo];
            const float nv = (v - mu) * rstd * ln_g[oo] + ln_b[oo];
            efs[el][oo]  = nv;
            efsB[el][oo] = (__bf16)nv;
        }
    }
    __syncthreads();

    // ---------------- GEMM3 (MFMA): efsB[64x128] @ cW1t^T -> silu -> *cW2 -> w per edge ----------------
    {
        f32x4 acc3[4][2];
        #pragma unroll
        for (int mt = 0; mt < 4; mt++) { acc3[mt][0] = z4; acc3[mt][1] = z4; }
        const __bf16* W3 = cW1t + (size_t)wv * 32 * HIDN;
        #pragma unroll
        for (int ks = 0; ks < 4; ks++) {
            const int kof = ks * 32 + lg * 8;
            bf16x8 b30 = *(const bf16x8*)(W3 + (size_t)lr * HIDN + kof);
            bf16x8 b31 = *(const bf16x8*)(W3 + (size_t)(16 + lr) * HIDN + kof);
            #pragma unroll
            for (int mt = 0; mt < 4; mt++) {
                bf16x8 a = *(const bf16x8*)(&efsB[mt * 16 + lr][kof]);
                acc3[mt][0] = MFMA(a, b30, acc3[mt][0]);
                acc3[mt][1] = MFMA(a, b31, acc3[mt][1]);
            }
        }
        const int c0 = wv * 32 + lr, c1 = c0 + 16;
        const float cbA = cb1[c0], cbB = cb1[c1];
        const float cwA = cW2[c0], cwB = cW2[c1];
        float pe[16];
        #pragma unroll
        for (int mt = 0; mt < 4; mt++)
            #pragma unroll
            for (int r = 0; r < 4; r++)
                pe[mt * 4 + r] = silu_f(acc3[mt][0][r] + cbA) * cwA
                               + silu_f(acc3[mt][1][r] + cbB) * cwB;
        #pragma unroll
        for (int d = 1; d < 16; d <<= 1)
            #pragma unroll
            for (int i = 0; i < 16; i++) pe[i] += __shfl_xor(pe[i], d);
        if (lr == 0) {
            #pragma unroll
            for (int mt = 0; mt < 4; mt++)
                #pragma unroll
                for (int r = 0; r < 4; r++)
                    atomicAdd(&wsum[mt * 16 + lg * 4 + r], pe[mt * 4 + r]);
        }
    }
    __syncthreads();

    // ---------------- coord scatter ----------------
    if (t < TE) {
        const float we = wsum[t];
        const int r = rowlds[t];
        atomicAdd(&coord_out[(size_t)r*3+0], cdiff[t][0] * we);
        atomicAdd(&coord_out[(size_t)r*3+1], cdiff[t][1] * we);
        atomicAdd(&coord_out[(size_t)r*3+2], cdiff[t][2] * we);
    }

    // ---------------- agg scatter (fp32 LN'd values) ----------------
    {
        const int o  = t & 127;
        const int gq = t >> 7;
        #pragma unroll
        for (int e2 = 0; e2 < 32; e2++) {
            const int ee = gq * 32 + e2;
            atomicAdd(&agg[(size_t)rowlds[ee] * HIDN + o], efs[ee][o]);
        }
    }
}

__global__ __launch_bounds__(256) void node_kernel(
    const float* __restrict__ h, const float* __restrict__ agg,
    const float* __restrict__ nW1, const float* __restrict__ nb1,
    const float* __restrict__ nW2, const float* __restrict__ nb2,
    float* __restrict__ h_out)
{
    __shared__ __align__(16) float xs[2*FIN][TN];       // [256][32]
    __shared__ __align__(16) float hid[TN][HIDN + 4];   // [32][132]

    const int t  = threadIdx.x;
    const int n0 = blockIdx.x * TN;

    {
        const int n = t >> 3;
        const int q = t & 7;
        const int nid = n0 + n;
        const bool ok = nid < NN;
        const float4* hr = reinterpret_cast<const float4*>(h + (size_t)nid * FIN);
        const float4* ar = reinterpret_cast<const float4*>(agg + (size_t)nid * FIN);
        #pragma unroll
        for (int j = 0; j < 4; j++) {
            const int f4 = q + 8*j;
            float4 v = ok ? hr[f4] : make_float4(0.f,0.f,0.f,0.f);
            xs[f4*4+0][n]=v.x; xs[f4*4+1][n]=v.y; xs[f4*4+2][n]=v.z; xs[f4*4+3][n]=v.w;
            float4 u = ok ? ar[f4] : make_float4(0.f,0.f,0.f,0.f);
            xs[FIN+f4*4+0][n]=u.x; xs[FIN+f4*4+1][n]=u.y; xs[FIN+f4*4+2][n]=u.z; xs[FIN+f4*4+3][n]=u.w;
        }
    }
    __syncthreads();

    const int o   = t & 127;
    const int g   = t >> 7;
    const int nb_ = g * 16;

    float acc[16];
    #pragma unroll
    for (int i = 0; i < 16; i++) acc[i] = 0.f;
    #pragma unroll 4
    for (int k = 0; k < 2*FIN; k++) {
        const float w = nW1[(size_t)k * HIDN + o];
        const float4* fr = reinterpret_cast<const float4*>(&xs[k][nb_]);
        #pragma unroll
        for (int c4 = 0; c4 < 4; c4++) {
            float4 v = fr[c4];
            acc[4*c4+0] = fmaf(v.x, w, acc[4*c4+0]);
            acc[4*c4+1] = fmaf(v.y, w, acc[4*c4+1]);
            acc[4*c4+2] = fmaf(v.z, w, acc[4*c4+2]);
            acc[4*c4+3] = fmaf(v.w, w, acc[4*c4+3]);
        }
    }
    {
        const float b1 = nb1[o];
        #pragma unroll
        for (int e = 0; e < 16; e++)
            hid[nb_+e][o] = silu_f(acc[e] + b1);
    }
    __syncthreads();

    float acc2[16];
    #pragma unroll
    for (int i = 0; i < 16; i++) acc2[i] = 0.f;
    for (int k = 0; k < HIDN; k++) {
        const float w = nW2[(size_t)k * FIN + o];
        #pragma unroll
        for (int e = 0; e < 16; e++)
            acc2[e] = fmaf(hid[nb_+e][k], w, acc2[e]);
    }
    const float b2 = nb2[o];
    #pragma unroll
    for (int e = 0; e < 16; e++) {
        const int nid = n0 + nb_ + e;
        if (nid < NN)
            h_out[(size_t)nid*FIN + o] = h[(size_t)nid*FIN + o] + acc2[e] + b2;
    }
}

extern "C" void kernel_launch(void* const* d_in, const int* in_sizes, int n_in,
                              void* d_out, int out_size, void* d_ws, size_t ws_size,
                              hipStream_t stream)
{
    (void)in_sizes; (void)n_in; (void)out_size; (void)ws_size;
    const float* h     = (const float*)d_in[0];
    const float* coord = (const float*)d_in[1];
    const int*   ei    = (const int*)d_in[2];
    const float* eW1   = (const float*)d_in[3];
    const float* eb1   = (const float*)d_in[4];
    const float* eW2   = (const float*)d_in[5];
    const float* eb2   = (const float*)d_in[6];
    const float* ln_g  = (const float*)d_in[7];
    const float* ln_b  = (const float*)d_in[8];
    const float* nW1   = (const float*)d_in[9];
    const float* nb1   = (const float*)d_in[10];
    const float* nW2   = (const float*)d_in[11];
    const float* nb2   = (const float*)d_in[12];
    const float* cW1   = (const float*)d_in[13];
    const float* cb1   = (const float*)d_in[14];
    const float* cW2   = (const float*)d_in[15];

    float* h_out     = (float*)d_out;
    float* coord_out = h_out + (size_t)NN * FIN;
    float* agg       = h_out;   // agg accumulates in the h_out region (aliased safely)

    // bf16 transposed weights in ws: eW1t [4*32*288] + eW2t [4*32*32] + cW1t [128*128]
    __bf16* eW1t = (__bf16*)d_ws;
    __bf16* eW2t = eW1t + 4 * 32 * K1;
    __bf16* cW1t = eW2t + 4 * HD * HD;
    // total = (36864 + 4096 + 16384) * 2 = 114,688 bytes of ws

    hipMemsetAsync(agg, 0, (size_t)NN * HIDN * sizeof(float), stream);
    hipMemcpyAsync(coord_out, coord, (size_t)NN * 3 * sizeof(float),
                   hipMemcpyDeviceToDevice, stream);
    wconv_kernel<<<(4 * 32 * K1 + 255) / 256, 256, 0, stream>>>(eW1, eW2, cW1, eW1t, eW2t, cW1t);

    edge_kernel<<<EE / TE, 256, 0, stream>>>(h, coord, ei, eW1t, eb1, eW2t, eb2,
                                             ln_g, ln_b, cW1t, cb1, cW2,
                                             agg, coord_out);
    node_kernel<<<(NN + TN - 1) / TN, 256, 0, stream>>>(h, agg, nW1, nb1, nW2, nb2, h_out);
}

// Round 7
// 610.639 us; speedup vs baseline: 2.9993x; 1.1247x over previous
//
#include <hip/hip_runtime.h>
#include <math.h>

#define NN 50000
#define EE 800000
#define FIN 128
#define HIDN 128
#define HD 32
#define FEATD 268
#define K1 288           // GEMM1 K padded to 9*32
#define KP1 296          // featsB LDS row stride (bf16 elems)
#define TE 64
#define TN 32

typedef __bf16 bf16x8 __attribute__((ext_vector_type(8)));
typedef __bf16 bf16x4 __attribute__((ext_vector_type(4)));
typedef float  f32x4  __attribute__((ext_vector_type(4)));

#define MFMA(a, b, c) __builtin_amdgcn_mfma_f32_16x16x32_bf16((a), (b), (c), 0, 0, 0)

__device__ __forceinline__ float silu_f(float x) {
    return x / (1.0f + __expf(-x));
}

// Transpose + bf16-convert weights into ws each launch (deterministic, ~5us).
__global__ void wconv_kernel(const float* __restrict__ eW1, const float* __restrict__ eW2,
                             const float* __restrict__ cW1,
                             __bf16* __restrict__ eW1t, __bf16* __restrict__ eW2t,
                             __bf16* __restrict__ cW1t)
{
    const int i = blockIdx.x * 256 + threadIdx.x;
    if (i < 4 * 32 * K1) {
        const int hh = i / (32 * K1), rs = i % (32 * K1), d = rs / K1, k = rs % K1;
        const float v = (k < FEATD) ? eW1[(size_t)hh * FEATD * HD + (size_t)k * HD + d] : 0.f;
        eW1t[i] = (__bf16)v;
    }
    if (i < 4 * HD * HD) {
        const int hh = i / (HD * HD), rs = i % (HD * HD), d = rs / HD, k = rs % HD;
        eW2t[i] = (__bf16)eW2[(size_t)hh * HD * HD + (size_t)k * HD + d];
    }
    if (i < HIDN * HIDN) {
        const int o = i / HIDN, k = i % HIDN;
        cW1t[i] = (__bf16)cW1[(size_t)k * HIDN + o];
    }
}

// 512 threads = 8 waves: wave wv2 = (head hh = wv2>>1, edge-half mh = wv2&1).
__global__ __launch_bounds__(512) void edge_kernel(
    const float* __restrict__ h, const float* __restrict__ coord,
    const int* __restrict__ ei,
    const __bf16* __restrict__ eW1t, const float* __restrict__ eb1,
    const __bf16* __restrict__ eW2t, const float* __restrict__ eb2,
    const float* __restrict__ ln_g, const float* __restrict__ ln_b,
    const __bf16* __restrict__ cW1t, const float* __restrict__ cb1,
    const float* __restrict__ cW2,
    float* __restrict__ agg, float* __restrict__ coord_out)
{
    // Region A: featsB bf16[64][296] (37,888B) -> later efs f32[64][132] (33,792B)
    // Region B: hidB  bf16[4][64][40] (20,480B) -> later efsB bf16[64][136] (17,408B)
    __shared__ __align__(16) unsigned char smemA[TE * KP1 * 2];
    __shared__ __align__(16) unsigned char smemB[4 * TE * 40 * 2];
    __shared__ float cdiff[TE][3];
    __shared__ int   rowlds[TE];
    __shared__ float wsum[TE];

    __bf16 (*featsB)[KP1] = (__bf16 (*)[KP1])smemA;
    float  (*efs)[132]    = (float  (*)[132])smemA;
    __bf16 (*efsB)[136]   = (__bf16 (*)[136])smemB;

    const int t  = threadIdx.x;
    const int e0 = blockIdx.x * TE;

    if (t < TE) wsum[t] = 0.f;

    // ---------------- Phase 0: gather h (bf16) + geometry into featsB ----------------
    {
        const int e = t >> 3;        // edge 0..63 (8 threads/edge)
        const int q = t & 7;
        const int r = ei[e0 + e];
        const int c = ei[EE + e0 + e];
        const float4* hr = (const float4*)(h + (size_t)r * FIN);
        const float4* hc = (const float4*)(h + (size_t)c * FIN);
        #pragma unroll
        for (int j = 0; j < 4; j++) {
            const int f4 = q + 8 * j;
            float4 v = hr[f4];
            bf16x4 bv = { (__bf16)v.x, (__bf16)v.y, (__bf16)v.z, (__bf16)v.w };
            *(bf16x4*)&featsB[e][f4 * 4] = bv;
            float4 u = hc[f4];
            bf16x4 bu = { (__bf16)u.x, (__bf16)u.y, (__bf16)u.z, (__bf16)u.w };
            *(bf16x4*)&featsB[e][FIN + f4 * 4] = bu;
        }
        if (q == 0) {
            rowlds[e] = r;
            const float cix = coord[(size_t)r*3+0], ciy = coord[(size_t)r*3+1], ciz = coord[(size_t)r*3+2];
            const float ckx = coord[(size_t)c*3+0], cky = coord[(size_t)c*3+1], ckz = coord[(size_t)c*3+2];
            const float dx = cix-ckx, dy = ciy-cky, dz = ciz-ckz;
            cdiff[e][0]=dx; cdiff[e][1]=dy; cdiff[e][2]=dz;
            const float radial = dx*dx + dy*dy + dz*dz;
            const float dist   = sqrtf(radial);
            const float dotv   = cix*ckx + ciy*cky + ciz*ckz;
            const float ia = 1.0f / (dist + 1e-8f);
            float ax = dx*ia, ay = dy*ia, az = dz*ia;
            const float cpx = ciy*ckz - ciz*cky;
            const float cpy = ciz*ckx - cix*ckz;
            const float cpz = cix*cky - ciy*ckx;
            const float cpn = sqrtf(cpx*cpx + cpy*cpy + cpz*cpz);
            const float ib = 1.0f / (cpn + 1e-8f);
            float bx = cpx*ib, by = cpy*ib, bz = cpz*ib;
            float cx = ay*bz - az*by;
            float cy = az*bx - ax*bz;
            float cz = ax*by - ay*bx;
            const float na = sqrtf(ax*ax + ay*ay + az*az);
            const float nb = sqrtf(bx*bx + by*by + bz*bz);
            const float nc = sqrtf(cx*cx + cy*cy + cz*cz);
            if (na < 1e-6f || nb < 1e-6f || nc < 1e-6f) {
                ax=1.f; bx=0.f; cx=0.f;
                ay=0.f; by=1.f; cy=0.f;
                az=0.f; bz=0.f; cz=1.f;
            }
            featsB[e][256]=(__bf16)radial; featsB[e][257]=(__bf16)dist; featsB[e][258]=(__bf16)dotv;
            featsB[e][259]=(__bf16)ax; featsB[e][260]=(__bf16)bx; featsB[e][261]=(__bf16)cx;
            featsB[e][262]=(__bf16)ay; featsB[e][263]=(__bf16)by; featsB[e][264]=(__bf16)cy;
            featsB[e][265]=(__bf16)az; featsB[e][266]=(__bf16)bz; featsB[e][267]=(__bf16)cz;
            #pragma unroll
            for (int k = FEATD; k < K1; k++) featsB[e][k] = (__bf16)0.f;
        }
    }
    __syncthreads();

    const int wv2  = t >> 6;          // wave 0..7
    const int hh   = wv2 >> 1;        // head (GEMM1/2) / col-group (GEMM3)
    const int mh   = wv2 & 1;         // edge-half: rows [mh*32, mh*32+32)
    const int lane = t & 63;
    const int lr   = lane & 15;       // fragment row/col index
    const int lg   = lane >> 4;       // k-group (0..3)

    __bf16* hidB = ((__bf16*)smemB) + hh * (TE * 40);

    const f32x4 z4 = { 0.f, 0.f, 0.f, 0.f };

    // ---------------- GEMM1 (MFMA): feats[64x288] @ eW1t^T -> hid per head ----------------
    {
        f32x4 acc[2][2];
        #pragma unroll
        for (int mti = 0; mti < 2; mti++) { acc[mti][0] = z4; acc[mti][1] = z4; }
        const __bf16* W1 = eW1t + (size_t)hh * 32 * K1;
        #pragma unroll
        for (int ks = 0; ks < 9; ks++) {
            const int kof = ks * 32 + lg * 8;
            bf16x8 b0 = *(const bf16x8*)(W1 + (size_t)lr * K1 + kof);
            bf16x8 b1 = *(const bf16x8*)(W1 + (size_t)(16 + lr) * K1 + kof);
            #pragma unroll
            for (int mti = 0; mti < 2; mti++) {
                bf16x8 a = *(const bf16x8*)(&featsB[(mh * 2 + mti) * 16 + lr][kof]);
                acc[mti][0] = MFMA(a, b0, acc[mti][0]);
                acc[mti][1] = MFMA(a, b1, acc[mti][1]);
            }
        }
        const float b1a = eb1[hh * HD + lr];
        const float b1b = eb1[hh * HD + 16 + lr];
        #pragma unroll
        for (int mti = 0; mti < 2; mti++) {
            #pragma unroll
            for (int r = 0; r < 4; r++) {
                const int erow = (mh * 2 + mti) * 16 + lg * 4 + r;
                hidB[erow * 40 + lr]      = (__bf16)silu_f(acc[mti][0][r] + b1a);
                hidB[erow * 40 + 16 + lr] = (__bf16)silu_f(acc[mti][1][r] + b1b);
            }
        }
    }
    __syncthreads();

    // ---------------- GEMM2 (MFMA): hid @ eW2t^T + b2 -> efs (fp32) ----------------
    {
        f32x4 acc2[2][2];
        #pragma unroll
        for (int mti = 0; mti < 2; mti++) { acc2[mti][0] = z4; acc2[mti][1] = z4; }
        const __bf16* W2 = eW2t + (size_t)hh * HD * HD;
        const int kof2 = lg * 8;
        bf16x8 b20 = *(const bf16x8*)(W2 + (size_t)lr * HD + kof2);
        bf16x8 b21 = *(const bf16x8*)(W2 + (size_t)(16 + lr) * HD + kof2);
        #pragma unroll
        for (int mti = 0; mti < 2; mti++) {
            bf16x8 a = *(const bf16x8*)(hidB + ((mh * 2 + mti) * 16 + lr) * 40 + kof2);
            acc2[mti][0] = MFMA(a, b20, acc2[mti][0]);
            acc2[mti][1] = MFMA(a, b21, acc2[mti][1]);
        }
        const float b2a = eb2[hh * HD + lr];
        const float b2b = eb2[hh * HD + 16 + lr];
        #pragma unroll
        for (int mti = 0; mti < 2; mti++) {
            #pragma unroll
            for (int r = 0; r < 4; r++) {
                const int erow = (mh * 2 + mti) * 16 + lg * 4 + r;
                efs[erow][hh * HD + lr]      = acc2[mti][0][r] + b2a;
                efs[erow][hh * HD + 16 + lr] = acc2[mti][1][r] + b2b;
            }
        }
    }
    __syncthreads();

    // ---------------- LayerNorm over 128 (8 threads/edge) ----------------
    {
        const int el = t >> 3;
        const int q8 = t & 7;
        float s = 0.f, s2 = 0.f;
        #pragma unroll
        for (int i = 0; i < 16; i++) {
            const float v = efs[el][q8 + 8 * i];
            s += v; s2 += v * v;
        }
        s  += __shfl_xor(s, 1);  s  += __shfl_xor(s, 2);  s  += __shfl_xor(s, 4);
        s2 += __shfl_xor(s2, 1); s2 += __shfl_xor(s2, 2); s2 += __shfl_xor(s2, 4);
        const float mu   = s * (1.f / 128.f);
        const float var  = s2 * (1.f / 128.f) - mu * mu;
        const float rstd = rsqrtf(var + 1e-5f);
        #pragma unroll
        for (int i = 0; i < 16; i++) {
            const int oo = q8 + 8 * i;
            const float v  = efs[el][oo];
            const float nv = (v - mu) * rstd * ln_g[oo] + ln_b[oo];
            efs[el][oo]  = nv;
            efsB[el][oo] = (__bf16)nv;
        }
    }
    __syncthreads();

    // ---------------- GEMM3 (MFMA): efsB @ cW1t^T -> silu -> *cW2 -> w per edge ----------------
    {
        f32x4 acc3[2][2];
        #pragma unroll
        for (int mti = 0; mti < 2; mti++) { acc3[mti][0] = z4; acc3[mti][1] = z4; }
        const __bf16* W3 = cW1t + (size_t)hh * 32 * HIDN;
        #pragma unroll
        for (int ks = 0; ks < 4; ks++) {
            const int kof = ks * 32 + lg * 8;
            bf16x8 b30 = *(const bf16x8*)(W3 + (size_t)lr * HIDN + kof);
            bf16x8 b31 = *(const bf16x8*)(W3 + (size_t)(16 + lr) * HIDN + kof);
            #pragma unroll
            for (int mti = 0; mti < 2; mti++) {
                bf16x8 a = *(const bf16x8*)(&efsB[(mh * 2 + mti) * 16 + lr][kof]);
                acc3[mti][0] = MFMA(a, b30, acc3[mti][0]);
                acc3[mti][1] = MFMA(a, b31, acc3[mti][1]);
            }
        }
        const int c0 = hh * 32 + lr, c1 = c0 + 16;
        const float cbA = cb1[c0], cbB = cb1[c1];
        const float cwA = cW2[c0], cwB = cW2[c1];
        float pe[8];
        #pragma unroll
        for (int mti = 0; mti < 2; mti++)
            #pragma unroll
            for (int r = 0; r < 4; r++)
                pe[mti * 4 + r] = silu_f(acc3[mti][0][r] + cbA) * cwA
                                + silu_f(acc3[mti][1][r] + cbB) * cwB;
        #pragma unroll
        for (int d = 1; d < 16; d <<= 1)
            #pragma unroll
            for (int i = 0; i < 8; i++) pe[i] += __shfl_xor(pe[i], d);
        if (lr == 0) {
            #pragma unroll
            for (int mti = 0; mti < 2; mti++)
                #pragma unroll
                for (int r = 0; r < 4; r++)
                    atomicAdd(&wsum[(mh * 2 + mti) * 16 + lg * 4 + r], pe[mti * 4 + r]);
        }
    }
    __syncthreads();

    // ---------------- coord scatter ----------------
    if (t < TE) {
        const float we = wsum[t];
        const int r = rowlds[t];
        atomicAdd(&coord_out[(size_t)r*3+0], cdiff[t][0] * we);
        atomicAdd(&coord_out[(size_t)r*3+1], cdiff[t][1] * we);
        atomicAdd(&coord_out[(size_t)r*3+2], cdiff[t][2] * we);
    }

    // ---------------- agg scatter (fp32 LN'd values) ----------------
    {
        const int o  = t & 127;
        const int gq = t >> 7;           // 0..3
        #pragma unroll
        for (int e2 = 0; e2 < 16; e2++) {
            const int ee = gq * 16 + e2;
            atomicAdd(&agg[(size_t)rowlds[ee] * HIDN + o], efs[ee][o]);
        }
    }
}

__global__ __launch_bounds__(256) void node_kernel(
    const float* __restrict__ h, const float* __restrict__ agg,
    const float* __restrict__ nW1, const float* __restrict__ nb1,
    const float* __restrict__ nW2, const float* __restrict__ nb2,
    float* __restrict__ h_out)
{
    __shared__ __align__(16) float xs[2*FIN][TN];       // [256][32]
    __shared__ __align__(16) float hid[TN][HIDN + 4];   // [32][132]

    const int t  = threadIdx.x;
    const int n0 = blockIdx.x * TN;

    {
        const int n = t >> 3;
        const int q = t & 7;
        const int nid = n0 + n;
        const bool ok = nid < NN;
        const float4* hr = reinterpret_cast<const float4*>(h + (size_t)nid * FIN);
        const float4* ar = reinterpret_cast<const float4*>(agg + (size_t)nid * FIN);
        #pragma unroll
        for (int j = 0; j < 4; j++) {
            const int f4 = q + 8*j;
            float4 v = ok ? hr[f4] : make_float4(0.f,0.f,0.f,0.f);
            xs[f4*4+0][n]=v.x; xs[f4*4+1][n]=v.y; xs[f4*4+2][n]=v.z; xs[f4*4+3][n]=v.w;
            float4 u = ok ? ar[f4] : make_float4(0.f,0.f,0.f,0.f);
            xs[FIN+f4*4+0][n]=u.x; xs[FIN+f4*4+1][n]=u.y; xs[FIN+f4*4+2][n]=u.z; xs[FIN+f4*4+3][n]=u.w;
        }
    }
    __syncthreads();

    const int o   = t & 127;
    const int g   = t >> 7;
    const int nb_ = g * 16;

    float acc[16];
    #pragma unroll
    for (int i = 0; i < 16; i++) acc[i] = 0.f;
    #pragma unroll 4
    for (int k = 0; k < 2*FIN; k++) {
        const float w = nW1[(size_t)k * HIDN + o];
        const float4* fr = reinterpret_cast<const float4*>(&xs[k][nb_]);
        #pragma unroll
        for (int c4 = 0; c4 < 4; c4++) {
            float4 v = fr[c4];
            acc[4*c4+0] = fmaf(v.x, w, acc[4*c4+0]);
            acc[4*c4+1] = fmaf(v.y, w, acc[4*c4+1]);
            acc[4*c4+2] = fmaf(v.z, w, acc[4*c4+2]);
            acc[4*c4+3] = fmaf(v.w, w, acc[4*c4+3]);
        }
    }
    {
        const float b1 = nb1[o];
        #pragma unroll
        for (int e = 0; e < 16; e++)
            hid[nb_+e][o] = silu_f(acc[e] + b1);
    }
    __syncthreads();

    float acc2[16];
    #pragma unroll
    for (int i = 0; i < 16; i++) acc2[i] = 0.f;
    for (int k = 0; k < HIDN; k++) {
        const float w = nW2[(size_t)k * FIN + o];
        #pragma unroll
        for (int e = 0; e < 16; e++)
            acc2[e] = fmaf(hid[nb_+e][k], w, acc2[e]);
    }
    const float b2 = nb2[o];
    #pragma unroll
    for (int e = 0; e < 16; e++) {
        const int nid = n0 + nb_ + e;
        if (nid < NN)
            h_out[(size_t)nid*FIN + o] = h[(size_t)nid*FIN + o] + acc2[e] + b2;
    }
}

extern "C" void kernel_launch(void* const* d_in, const int* in_sizes, int n_in,
                              void* d_out, int out_size, void* d_ws, size_t ws_size,
                              hipStream_t stream)
{
    (void)in_sizes; (void)n_in; (void)out_size; (void)ws_size;
    const float* h     = (const float*)d_in[0];
    const float* coord = (const float*)d_in[1];
    const int*   ei    = (const int*)d_in[2];
    const float* eW1   = (const float*)d_in[3];
    const float* eb1   = (const float*)d_in[4];
    const float* eW2   = (const float*)d_in[5];
    const float* eb2   = (const float*)d_in[6];
    const float* ln_g  = (const float*)d_in[7];
    const float* ln_b  = (const float*)d_in[8];
    const float* nW1   = (const float*)d_in[9];
    const float* nb1   = (const float*)d_in[10];
    const float* nW2   = (const float*)d_in[11];
    const float* nb2   = (const float*)d_in[12];
    const float* cW1   = (const float*)d_in[13];
    const float* cb1   = (const float*)d_in[14];
    const float* cW2   = (const float*)d_in[15];

    float* h_out     = (float*)d_out;
    float* coord_out = h_out + (size_t)NN * FIN;
    float* agg       = h_out;   // agg accumulates in the h_out region (aliased safely)

    __bf16* eW1t = (__bf16*)d_ws;
    __bf16* eW2t = eW1t + 4 * 32 * K1;
    __bf16* cW1t = eW2t + 4 * HD * HD;

    hipMemsetAsync(agg, 0, (size_t)NN * HIDN * sizeof(float), stream);
    hipMemcpyAsync(coord_out, coord, (size_t)NN * 3 * sizeof(float),
                   hipMemcpyDeviceToDevice, stream);
    wconv_kernel<<<(4 * 32 * K1 + 255) / 256, 256, 0, stream>>>(eW1, eW2, cW1, eW1t, eW2t, cW1t);

    edge_kernel<<<EE / TE, 512, 0, stream>>>(h, coord, ei, eW1t, eb1, eW2t, eb2,
                                             ln_g, ln_b, cW1t, cb1, cW2,
                                             agg, coord_out);
    node_kernel<<<(NN + TN - 1) / TN, 256, 0, stream>>>(h, agg, nW1, nb1, nW2, nb2, h_out);
}

// Round 8
// 456.897 us; speedup vs baseline: 4.0086x; 1.3365x over previous
//
#include <hip/hip_runtime.h>
#include <hip/hip_bf16.h>
#include <math.h>

#define NN 50000
#define EE 800000
#define FIN 128
#define HIDN 128
#define HD 32
#define FEATD 268
#define K1 288           // GEMM1 K padded to 9*32
#define KP1 296          // featsB LDS row stride (bf16 elems)
#define TE 64
#define TN2 64

typedef __bf16 bf16x8 __attribute__((ext_vector_type(8)));
typedef __bf16 bf16x4 __attribute__((ext_vector_type(4)));
typedef float  f32x4  __attribute__((ext_vector_type(4)));

#define MFMA(a, b, c) __builtin_amdgcn_mfma_f32_16x16x32_bf16((a), (b), (c), 0, 0, 0)

__device__ __forceinline__ float silu_f(float x) {
    return x / (1.0f + __expf(-x));
}

// Transpose + bf16-convert all weights into ws each launch (deterministic, ~5us).
// eW1t: [4][32][288]  from eW1 [4][268][32] (k>=268 zero)
// eW2t: [4][32][32]   from eW2 [4][32][32]
// cW1t: [128][128]    from cW1 [128][128]
// nW1t: [128][256]    from nW1 [256][128]
// nW2t: [128][128]    from nW2 [128][128]
__global__ void wconv_kernel(const float* __restrict__ eW1, const float* __restrict__ eW2,
                             const float* __restrict__ cW1, const float* __restrict__ nW1,
                             const float* __restrict__ nW2,
                             __bf16* __restrict__ eW1t, __bf16* __restrict__ eW2t,
                             __bf16* __restrict__ cW1t, __bf16* __restrict__ nW1t,
                             __bf16* __restrict__ nW2t)
{
    const int i = blockIdx.x * 256 + threadIdx.x;
    if (i < 4 * 32 * K1) {
        const int hh = i / (32 * K1), rs = i % (32 * K1), d = rs / K1, k = rs % K1;
        const float v = (k < FEATD) ? eW1[(size_t)hh * FEATD * HD + (size_t)k * HD + d] : 0.f;
        eW1t[i] = (__bf16)v;
    }
    if (i < 4 * HD * HD) {
        const int hh = i / (HD * HD), rs = i % (HD * HD), d = rs / HD, k = rs % HD;
        eW2t[i] = (__bf16)eW2[(size_t)hh * HD * HD + (size_t)k * HD + d];
    }
    if (i < HIDN * HIDN) {
        const int o = i / HIDN, k = i % HIDN;
        cW1t[i] = (__bf16)cW1[(size_t)k * HIDN + o];
    }
    if (i < HIDN * (2 * FIN)) {
        const int o = i / (2 * FIN), k = i % (2 * FIN);
        nW1t[i] = (__bf16)nW1[(size_t)k * HIDN + o];
    }
    if (i < FIN * HIDN) {
        const int o = i / HIDN, k = i % HIDN;
        nW2t[i] = (__bf16)nW2[(size_t)k * FIN + o];
    }
}

// 512 threads = 8 waves: wave wv2 = (head hh = wv2>>1, edge-half mh = wv2&1).
// agg is accumulated as packed 2xbf16 atomics into the UPPER 256B of each
// h_out row: addr = hout + row*512B + 256B + pair*4B.
__global__ __launch_bounds__(512) void edge_kernel(
    const float* __restrict__ h, const float* __restrict__ coord,
    const int* __restrict__ ei,
    const __bf16* __restrict__ eW1t, const float* __restrict__ eb1,
    const __bf16* __restrict__ eW2t, const float* __restrict__ eb2,
    const float* __restrict__ ln_g, const float* __restrict__ ln_b,
    const __bf16* __restrict__ cW1t, const float* __restrict__ cb1,
    const float* __restrict__ cW2,
    float* __restrict__ houtbase, float* __restrict__ coord_out)
{
    // Region A: featsB bf16[64][296] (37,888B) -> later efs f32[64][132] (33,792B)
    // Region B: hidB  bf16[4][64][40] (20,480B) -> later efsB bf16[64][136] (17,408B)
    __shared__ __align__(16) unsigned char smemA[TE * KP1 * 2];
    __shared__ __align__(16) unsigned char smemB[4 * TE * 40 * 2];
    __shared__ float cdiff[TE][3];
    __shared__ int   rowlds[TE];
    __shared__ float wsum[TE];

    __bf16 (*featsB)[KP1] = (__bf16 (*)[KP1])smemA;
    float  (*efs)[132]    = (float  (*)[132])smemA;
    __bf16 (*efsB)[136]   = (__bf16 (*)[136])smemB;

    const int t  = threadIdx.x;
    const int e0 = blockIdx.x * TE;

    if (t < TE) wsum[t] = 0.f;

    // ---------------- Phase 0: gather h (bf16) + geometry into featsB ----------------
    {
        const int e = t >> 3;        // edge 0..63 (8 threads/edge)
        const int q = t & 7;
        const int r = ei[e0 + e];
        const int c = ei[EE + e0 + e];
        const float4* hr = (const float4*)(h + (size_t)r * FIN);
        const float4* hc = (const float4*)(h + (size_t)c * FIN);
        #pragma unroll
        for (int j = 0; j < 4; j++) {
            const int f4 = q + 8 * j;
            float4 v = hr[f4];
            bf16x4 bv = { (__bf16)v.x, (__bf16)v.y, (__bf16)v.z, (__bf16)v.w };
            *(bf16x4*)&featsB[e][f4 * 4] = bv;
            float4 u = hc[f4];
            bf16x4 bu = { (__bf16)u.x, (__bf16)u.y, (__bf16)u.z, (__bf16)u.w };
            *(bf16x4*)&featsB[e][FIN + f4 * 4] = bu;
        }
        if (q == 0) {
            rowlds[e] = r;
            const float cix = coord[(size_t)r*3+0], ciy = coord[(size_t)r*3+1], ciz = coord[(size_t)r*3+2];
            const float ckx = coord[(size_t)c*3+0], cky = coord[(size_t)c*3+1], ckz = coord[(size_t)c*3+2];
            const float dx = cix-ckx, dy = ciy-cky, dz = ciz-ckz;
            cdiff[e][0]=dx; cdiff[e][1]=dy; cdiff[e][2]=dz;
            const float radial = dx*dx + dy*dy + dz*dz;
            const float dist   = sqrtf(radial);
            const float dotv   = cix*ckx + ciy*cky + ciz*ckz;
            const float ia = 1.0f / (dist + 1e-8f);
            float ax = dx*ia, ay = dy*ia, az = dz*ia;
            const float cpx = ciy*ckz - ciz*cky;
            const float cpy = ciz*ckx - cix*ckz;
            const float cpz = cix*cky - ciy*ckx;
            const float cpn = sqrtf(cpx*cpx + cpy*cpy + cpz*cpz);
            const float ib = 1.0f / (cpn + 1e-8f);
            float bx = cpx*ib, by = cpy*ib, bz = cpz*ib;
            float cx = ay*bz - az*by;
            float cy = az*bx - ax*bz;
            float cz = ax*by - ay*bx;
            const float na = sqrtf(ax*ax + ay*ay + az*az);
            const float nb = sqrtf(bx*bx + by*by + bz*bz);
            const float nc = sqrtf(cx*cx + cy*cy + cz*cz);
            if (na < 1e-6f || nb < 1e-6f || nc < 1e-6f) {
                ax=1.f; bx=0.f; cx=0.f;
                ay=0.f; by=1.f; cy=0.f;
                az=0.f; bz=0.f; cz=1.f;
            }
            featsB[e][256]=(__bf16)radial; featsB[e][257]=(__bf16)dist; featsB[e][258]=(__bf16)dotv;
            featsB[e][259]=(__bf16)ax; featsB[e][260]=(__bf16)bx; featsB[e][261]=(__bf16)cx;
            featsB[e][262]=(__bf16)ay; featsB[e][263]=(__bf16)by; featsB[e][264]=(__bf16)cy;
            featsB[e][265]=(__bf16)az; featsB[e][266]=(__bf16)bz; featsB[e][267]=(__bf16)cz;
            #pragma unroll
            for (int k = FEATD; k < K1; k++) featsB[e][k] = (__bf16)0.f;
        }
    }
    __syncthreads();

    const int wv2  = t >> 6;          // wave 0..7
    const int hh   = wv2 >> 1;        // head (GEMM1/2) / col-group (GEMM3)
    const int mh   = wv2 & 1;         // edge-half: rows [mh*32, mh*32+32)
    const int lane = t & 63;
    const int lr   = lane & 15;       // fragment row/col index
    const int lg   = lane >> 4;       // k-group (0..3)

    __bf16* hidB = ((__bf16*)smemB) + hh * (TE * 40);

    const f32x4 z4 = { 0.f, 0.f, 0.f, 0.f };

    // ---------------- GEMM1 (MFMA): feats[64x288] @ eW1t^T -> hid per head ----------------
    {
        f32x4 acc[2][2];
        #pragma unroll
        for (int mti = 0; mti < 2; mti++) { acc[mti][0] = z4; acc[mti][1] = z4; }
        const __bf16* W1 = eW1t + (size_t)hh * 32 * K1;
        #pragma unroll
        for (int ks = 0; ks < 9; ks++) {
            const int kof = ks * 32 + lg * 8;
            bf16x8 b0 = *(const bf16x8*)(W1 + (size_t)lr * K1 + kof);
            bf16x8 b1 = *(const bf16x8*)(W1 + (size_t)(16 + lr) * K1 + kof);
            #pragma unroll
            for (int mti = 0; mti < 2; mti++) {
                bf16x8 a = *(const bf16x8*)(&featsB[(mh * 2 + mti) * 16 + lr][kof]);
                acc[mti][0] = MFMA(a, b0, acc[mti][0]);
                acc[mti][1] = MFMA(a, b1, acc[mti][1]);
            }
        }
        const float b1a = eb1[hh * HD + lr];
        const float b1b = eb1[hh * HD + 16 + lr];
        #pragma unroll
        for (int mti = 0; mti < 2; mti++) {
            #pragma unroll
            for (int r = 0; r < 4; r++) {
                const int erow = (mh * 2 + mti) * 16 + lg * 4 + r;
                hidB[erow * 40 + lr]      = (__bf16)silu_f(acc[mti][0][r] + b1a);
                hidB[erow * 40 + 16 + lr] = (__bf16)silu_f(acc[mti][1][r] + b1b);
            }
        }
    }
    __syncthreads();

    // ---------------- GEMM2 (MFMA): hid @ eW2t^T + b2 -> efs (fp32) ----------------
    {
        f32x4 acc2[2][2];
        #pragma unroll
        for (int mti = 0; mti < 2; mti++) { acc2[mti][0] = z4; acc2[mti][1] = z4; }
        const __bf16* W2 = eW2t + (size_t)hh * HD * HD;
        const int kof2 = lg * 8;
        bf16x8 b20 = *(const bf16x8*)(W2 + (size_t)lr * HD + kof2);
        bf16x8 b21 = *(const bf16x8*)(W2 + (size_t)(16 + lr) * HD + kof2);
        #pragma unroll
        for (int mti = 0; mti < 2; mti++) {
            bf16x8 a = *(const bf16x8*)(hidB + ((mh * 2 + mti) * 16 + lr) * 40 + kof2);
            acc2[mti][0] = MFMA(a, b20, acc2[mti][0]);
            acc2[mti][1] = MFMA(a, b21, acc2[mti][1]);
        }
        const float b2a = eb2[hh * HD + lr];
        const float b2b = eb2[hh * HD + 16 + lr];
        #pragma unroll
        for (int mti = 0; mti < 2; mti++) {
            #pragma unroll
            for (int r = 0; r < 4; r++) {
                const int erow = (mh * 2 + mti) * 16 + lg * 4 + r;
                efs[erow][hh * HD + lr]      = acc2[mti][0][r] + b2a;
                efs[erow][hh * HD + 16 + lr] = acc2[mti][1][r] + b2b;
            }
        }
    }
    __syncthreads();

    // ---------------- LayerNorm over 128 (8 threads/edge) ----------------
    {
        const int el = t >> 3;
        const int q8 = t & 7;
        float s = 0.f, s2 = 0.f;
        #pragma unroll
        for (int i = 0; i < 16; i++) {
            const float v = efs[el][q8 + 8 * i];
            s += v; s2 += v * v;
        }
        s  += __shfl_xor(s, 1);  s  += __shfl_xor(s, 2);  s  += __shfl_xor(s, 4);
        s2 += __shfl_xor(s2, 1); s2 += __shfl_xor(s2, 2); s2 += __shfl_xor(s2, 4);
        const float mu   = s * (1.f / 128.f);
        const float var  = s2 * (1.f / 128.f) - mu * mu;
        const float rstd = rsqrtf(var + 1e-5f);
        #pragma unroll
        for (int i = 0; i < 16; i++) {
            const int oo = q8 + 8 * i;
            const float v  = efs[el][oo];
            const float nv = (v - mu) * rstd * ln_g[oo] + ln_b[oo];
            efs[el][oo]  = nv;
            efsB[el][oo] = (__bf16)nv;
        }
    }
    __syncthreads();

    // ---------------- GEMM3 (MFMA): efsB @ cW1t^T -> silu -> *cW2 -> w per edge ----------------
    {
        f32x4 acc3[2][2];
        #pragma unroll
        for (int mti = 0; mti < 2; mti++) { acc3[mti][0] = z4; acc3[mti][1] = z4; }
        const __bf16* W3 = cW1t + (size_t)hh * 32 * HIDN;
        #pragma unroll
        for (int ks = 0; ks < 4; ks++) {
            const int kof = ks * 32 + lg * 8;
            bf16x8 b30 = *(const bf16x8*)(W3 + (size_t)lr * HIDN + kof);
            bf16x8 b31 = *(const bf16x8*)(W3 + (size_t)(16 + lr) * HIDN + kof);
            #pragma unroll
            for (int mti = 0; mti < 2; mti++) {
                bf16x8 a = *(const bf16x8*)(&efsB[(mh * 2 + mti) * 16 + lr][kof]);
                acc3[mti][0] = MFMA(a, b30, acc3[mti][0]);
                acc3[mti][1] = MFMA(a, b31, acc3[mti][1]);
            }
        }
        const int c0 = hh * 32 + lr, c1 = c0 + 16;
        const float cbA = cb1[c0], cbB = cb1[c1];
        const float cwA = cW2[c0], cwB = cW2[c1];
        float pe[8];
        #pragma unroll
        for (int mti = 0; mti < 2; mti++)
            #pragma unroll
            for (int r = 0; r < 4; r++)
                pe[mti * 4 + r] = silu_f(acc3[mti][0][r] + cbA) * cwA
                                + silu_f(acc3[mti][1][r] + cbB) * cwB;
        #pragma unroll
        for (int d = 1; d < 16; d <<= 1)
            #pragma unroll
            for (int i = 0; i < 8; i++) pe[i] += __shfl_xor(pe[i], d);
        if (lr == 0) {
            #pragma unroll
            for (int mti = 0; mti < 2; mti++)
                #pragma unroll
                for (int r = 0; r < 4; r++)
                    atomicAdd(&wsum[(mh * 2 + mti) * 16 + lg * 4 + r], pe[mti * 4 + r]);
        }
    }
    __syncthreads();

    // ---------------- coord scatter ----------------
    if (t < TE) {
        const float we = wsum[t];
        const int r = rowlds[t];
        atomicAdd(&coord_out[(size_t)r*3+0], cdiff[t][0] * we);
        atomicAdd(&coord_out[(size_t)r*3+1], cdiff[t][1] * we);
        atomicAdd(&coord_out[(size_t)r*3+2], cdiff[t][2] * we);
    }

    // ---------------- agg scatter: packed 2xbf16 atomics ----------------
    {
        const int p  = t & 63;           // feature-pair index (0..63)
        const int gq = t >> 6;           // 0..7
        #pragma unroll
        for (int e2 = 0; e2 < 8; e2++) {
            const int ee = gq * 8 + e2;
            const float lo = efs[ee][2 * p];
            const float hi = efs[ee][2 * p + 1];
            __hip_bfloat162 pk;
            pk.x = __float2bfloat16(lo);
            pk.y = __float2bfloat16(hi);
            __hip_bfloat162* addr = (__hip_bfloat162*)
                ((char*)houtbase + (size_t)rowlds[ee] * 512 + 256 + p * 4);
            unsafeAtomicAdd(addr, pk);
        }
    }
}

// 512 threads = 8 waves: wave = (col-group hh2 = wv>>1, node-half mh = wv&1).
// Reads agg (packed bf16) from upper 256B of each h_out row, then overwrites
// the full row with the final f32 h_out (own rows only; staged first).
__global__ __launch_bounds__(512) void node_kernel(
    const float* __restrict__ h,
    const __bf16* __restrict__ nW1t, const float* __restrict__ nb1,
    const __bf16* __restrict__ nW2t, const float* __restrict__ nb2,
    float* __restrict__ h_out)
{
    __shared__ __align__(16) __bf16 featsN[TN2][264];   // [64][256+8]
    __shared__ __align__(16) __bf16 hidN[TN2][136];     // [64][128+8]

    const int t  = threadIdx.x;
    const int n0 = blockIdx.x * TN2;

    // ---------------- Phase 0: stage h (f32->bf16) and packed agg ----------------
    {
        const int n = t >> 3;
        const int q = t & 7;
        const int nid = n0 + n;
        const bool ok = nid < NN;
        const float4* hr = (const float4*)(h + (size_t)nid * FIN);
        #pragma unroll
        for (int j = 0; j < 4; j++) {
            const int f4 = q + 8 * j;
            float4 v = ok ? hr[f4] : make_float4(0.f, 0.f, 0.f, 0.f);
            bf16x4 bv = { (__bf16)v.x, (__bf16)v.y, (__bf16)v.z, (__bf16)v.w };
            *(bf16x4*)&featsN[n][f4 * 4] = bv;
        }
        const uint4* ar = (const uint4*)((const char*)h_out + (size_t)nid * 512 + 256);
        #pragma unroll
        for (int j = 0; j < 2; j++) {
            const int w4 = q * 2 + j;                 // uint4 index 0..15
            uint4 u = ok ? ar[w4] : make_uint4(0u, 0u, 0u, 0u);
            *(uint4*)&featsN[n][FIN + w4 * 8] = u;    // 8 bf16 per uint4
        }
    }
    __syncthreads();

    const int wv2  = t >> 6;
    const int hh2  = wv2 >> 1;        // output col-group (0..3)
    const int mh   = wv2 & 1;         // node-half
    const int lane = t & 63;
    const int lr   = lane & 15;
    const int lg   = lane >> 4;

    const f32x4 z4 = { 0.f, 0.f, 0.f, 0.f };

    // ---------------- GEMM1n (MFMA): featsN[64x256] @ nW1t^T -> silu -> hidN ----------------
    {
        f32x4 acc[2][2];
        #pragma unroll
        for (int mti = 0; mti < 2; mti++) { acc[mti][0] = z4; acc[mti][1] = z4; }
        const __bf16* W1 = nW1t + (size_t)hh2 * 32 * 256;
        #pragma unroll
        for (int ks = 0; ks < 8; ks++) {
            const int kof = ks * 32 + lg * 8;
            bf16x8 b0 = *(const bf16x8*)(W1 + (size_t)lr * 256 + kof);
            bf16x8 b1 = *(const bf16x8*)(W1 + (size_t)(16 + lr) * 256 + kof);
            #pragma unroll
            for (int mti = 0; mti < 2; mti++) {
                bf16x8 a = *(const bf16x8*)(&featsN[(mh * 2 + mti) * 16 + lr][kof]);
                acc[mti][0] = MFMA(a, b0, acc[mti][0]);
                acc[mti][1] = MFMA(a, b1, acc[mti][1]);
            }
        }
        const float b1a = nb1[hh2 * 32 + lr];
        const float b1b = nb1[hh2 * 32 + 16 + lr];
        #pragma unroll
        for (int mti = 0; mti < 2; mti++) {
            #pragma unroll
            for (int r = 0; r < 4; r++) {
                const int erow = (mh * 2 + mti) * 16 + lg * 4 + r;
                hidN[erow][hh2 * 32 + lr]      = (__bf16)silu_f(acc[mti][0][r] + b1a);
                hidN[erow][hh2 * 32 + 16 + lr] = (__bf16)silu_f(acc[mti][1][r] + b1b);
            }
        }
    }
    __syncthreads();

    // ---------------- GEMM2n (MFMA): hidN[64x128] @ nW2t^T + nb2 + h -> h_out ----------------
    {
        f32x4 acc2[2][2];
        #pragma unroll
        for (int mti = 0; mti < 2; mti++) { acc2[mti][0] = z4; acc2[mti][1] = z4; }
        const __bf16* W2 = nW2t + (size_t)hh2 * 32 * 128;
        #pragma unroll
        for (int ks = 0; ks < 4; ks++) {
            const int kof = ks * 32 + lg * 8;
            bf16x8 b0 = *(const bf16x8*)(W2 + (size_t)lr * 128 + kof);
            bf16x8 b1 = *(const bf16x8*)(W2 + (size_t)(16 + lr) * 128 + kof);
            #pragma unroll
            for (int mti = 0; mti < 2; mti++) {
                bf16x8 a = *(const bf16x8*)(&hidN[(mh * 2 + mti) * 16 + lr][kof]);
                acc2[mti][0] = MFMA(a, b0, acc2[mti][0]);
                acc2[mti][1] = MFMA(a, b1, acc2[mti][1]);
            }
        }
        const float b2a = nb2[hh2 * 32 + lr];
        const float b2b = nb2[hh2 * 32 + 16 + lr];
        const int c0 = hh2 * 32 + lr, c1 = c0 + 16;
        #pragma unroll
        for (int mti = 0; mti < 2; mti++) {
            #pragma unroll
            for (int r = 0; r < 4; r++) {
                const int erow = (mh * 2 + mti) * 16 + lg * 4 + r;
                const int nid  = n0 + erow;
                if (nid < NN) {
                    h_out[(size_t)nid * FIN + c0] = h[(size_t)nid * FIN + c0] + acc2[mti][0][r] + b2a;
                    h_out[(size_t)nid * FIN + c1] = h[(size_t)nid * FIN + c1] + acc2[mti][1][r] + b2b;
                }
            }
        }
    }
}

extern "C" void kernel_launch(void* const* d_in, const int* in_sizes, int n_in,
                              void* d_out, int out_size, void* d_ws, size_t ws_size,
                              hipStream_t stream)
{
    (void)in_sizes; (void)n_in; (void)out_size; (void)ws_size;
    const float* h     = (const float*)d_in[0];
    const float* coord = (const float*)d_in[1];
    const int*   ei    = (const int*)d_in[2];
    const float* eW1   = (const float*)d_in[3];
    const float* eb1   = (const float*)d_in[4];
    const float* eW2   = (const float*)d_in[5];
    const float* eb2   = (const float*)d_in[6];
    const float* ln_g  = (const float*)d_in[7];
    const float* ln_b  = (const float*)d_in[8];
    const float* nW1   = (const float*)d_in[9];
    const float* nb1   = (const float*)d_in[10];
    const float* nW2   = (const float*)d_in[11];
    const float* nb2   = (const float*)d_in[12];
    const float* cW1   = (const float*)d_in[13];
    const float* cb1   = (const float*)d_in[14];
    const float* cW2   = (const float*)d_in[15];

    float* h_out     = (float*)d_out;
    float* coord_out = h_out + (size_t)NN * FIN;

    // bf16 transposed weights in ws
    __bf16* eW1t = (__bf16*)d_ws;               // 36864
    __bf16* eW2t = eW1t + 4 * 32 * K1;          // 4096
    __bf16* cW1t = eW2t + 4 * HD * HD;          // 16384
    __bf16* nW1t = cW1t + HIDN * HIDN;          // 32768
    __bf16* nW2t = nW1t + HIDN * (2 * FIN);     // 16384  (total ~213KB of ws)

    // zero h_out region (packed-bf16 agg accumulates in upper 256B of each row)
    hipMemsetAsync(h_out, 0, (size_t)NN * FIN * sizeof(float), stream);
    hipMemcpyAsync(coord_out, coord, (size_t)NN * 3 * sizeof(float),
                   hipMemcpyDeviceToDevice, stream);
    wconv_kernel<<<(4 * 32 * K1 + 255) / 256, 256, 0, stream>>>(
        eW1, eW2, cW1, nW1, nW2, eW1t, eW2t, cW1t, nW1t, nW2t);

    edge_kernel<<<EE / TE, 512, 0, stream>>>(h, coord, ei, eW1t, eb1, eW2t, eb2,
                                             ln_g, ln_b, cW1t, cb1, cW2,
                                             h_out, coord_out);
    node_kernel<<<(NN + TN2 - 1) / TN2, 512, 0, stream>>>(h, nW1t, nb1, nW2t, nb2, h_out);
}

// Round 10
// 435.612 us; speedup vs baseline: 4.2045x; 1.0489x over previous
//
#include <hip/hip_runtime.h>
#include <hip/hip_bf16.h>
#include <math.h>

#define NN 50000
#define EE 800000
#define FIN 128
#define HIDN 128
#define HD 32
#define FEATD 268
#define K1 288           // GEMM1 K padded to 9*32
#define KP1 296          // featsB LDS row stride (bf16 elems)
#define TE 64
#define TN2 64

typedef __bf16 bf16x8 __attribute__((ext_vector_type(8)));
typedef __bf16 bf16x4 __attribute__((ext_vector_type(4)));
typedef float  f32x4  __attribute__((ext_vector_type(4)));

#define MFMA(a, b, c) __builtin_amdgcn_mfma_f32_16x16x32_bf16((a), (b), (c), 0, 0, 0)

__device__ __forceinline__ float silu_f(float x) {
    return x / (1.0f + __expf(-x));
}

// Transpose + bf16-convert all weights into ws each launch (deterministic).
__global__ void wconv_kernel(const float* __restrict__ eW1, const float* __restrict__ eW2,
                             const float* __restrict__ cW1, const float* __restrict__ nW1,
                             const float* __restrict__ nW2,
                             __bf16* __restrict__ eW1t, __bf16* __restrict__ eW2t,
                             __bf16* __restrict__ cW1t, __bf16* __restrict__ nW1t,
                             __bf16* __restrict__ nW2t)
{
    const int i = blockIdx.x * 256 + threadIdx.x;
    if (i < 4 * 32 * K1) {
        const int hh = i / (32 * K1), rs = i % (32 * K1), d = rs / K1, k = rs % K1;
        const float v = (k < FEATD) ? eW1[(size_t)hh * FEATD * HD + (size_t)k * HD + d] : 0.f;
        eW1t[i] = (__bf16)v;
    }
    if (i < 4 * HD * HD) {
        const int hh = i / (HD * HD), rs = i % (HD * HD), d = rs / HD, k = rs % HD;
        eW2t[i] = (__bf16)eW2[(size_t)hh * HD * HD + (size_t)k * HD + d];
    }
    if (i < HIDN * HIDN) {
        const int o = i / HIDN, k = i % HIDN;
        cW1t[i] = (__bf16)cW1[(size_t)k * HIDN + o];
    }
    if (i < HIDN * (2 * FIN)) {
        const int o = i / (2 * FIN), k = i % (2 * FIN);
        nW1t[i] = (__bf16)nW1[(size_t)k * HIDN + o];
    }
    if (i < FIN * HIDN) {
        const int o = i / HIDN, k = i % HIDN;
        nW2t[i] = (__bf16)nW2[(size_t)k * FIN + o];
    }
}

// Convert h (f32 [NN][128]) -> bf16, stored in the LOWER 256B of each 512B
// h_out row (upper 256B holds the packed-bf16 agg accumulator).
__global__ __launch_bounds__(256) void hconv_kernel(const float* __restrict__ h,
                                                    float* __restrict__ houtbase)
{
    const int i = blockIdx.x * 256 + threadIdx.x;   // one per 8 elems
    if (i >= NN * FIN / 8) return;
    const int row = i >> 4;          // 16 threads per row
    const int c8  = i & 15;          // 8-elem chunk within row
    const float4* src = (const float4*)(h + (size_t)row * FIN + c8 * 8);
    float4 a = src[0], b = src[1];
    bf16x8 v = { (__bf16)a.x, (__bf16)a.y, (__bf16)a.z, (__bf16)a.w,
                 (__bf16)b.x, (__bf16)b.y, (__bf16)b.z, (__bf16)b.w };
    *(bf16x8*)((char*)houtbase + (size_t)row * 512 + c8 * 16) = v;
}

// 512 threads = 8 waves: wave wv2 = (head hh = wv2>>1, edge-half mh = wv2&1).
// h gathered as bf16 from lower 256B of h_out rows; agg accumulated as packed
// 2xbf16 atomics into the UPPER 256B of each h_out row.
__global__ __launch_bounds__(512) void edge_kernel(
    const float* __restrict__ coord,
    const int* __restrict__ ei,
    const __bf16* __restrict__ eW1t, const float* __restrict__ eb1,
    const __bf16* __restrict__ eW2t, const float* __restrict__ eb2,
    const float* __restrict__ ln_g, const float* __restrict__ ln_b,
    const __bf16* __restrict__ cW1t, const float* __restrict__ cb1,
    const float* __restrict__ cW2,
    float* __restrict__ houtbase, float* __restrict__ coord_out)
{
    // Region A: featsB bf16[64][296] (37,888B) -> later efs f32[64][132] (33,792B)
    // Region B: hidB  bf16[4][64][40] (20,480B) -> later efsB bf16[64][136] (17,408B)
    __shared__ __align__(16) unsigned char smemA[TE * KP1 * 2];
    __shared__ __align__(16) unsigned char smemB[4 * TE * 40 * 2];
    __shared__ float cdiff[TE][3];
    __shared__ int   rowlds[TE];
    __shared__ float wsum[TE];

    __bf16 (*featsB)[KP1] = (__bf16 (*)[KP1])smemA;
    float  (*efs)[132]    = (float  (*)[132])smemA;
    __bf16 (*efsB)[136]   = (__bf16 (*)[136])smemB;

    const int t  = threadIdx.x;
    const int e0 = blockIdx.x * TE;

    if (t < TE) wsum[t] = 0.f;

    // ---------------- Phase 0: gather hB (bf16) + geometry into featsB ----------------
    {
        const int e = t >> 3;        // edge 0..63 (8 threads/edge)
        const int q = t & 7;
        const int r = ei[e0 + e];
        const int c = ei[EE + e0 + e];
        // each thread: two 16B chunks of hB[r] and two of hB[c] (16 chunks/row total)
        #pragma unroll
        for (int j = 0; j < 2; j++) {
            const int c16 = q + 8 * j;   // 16B-chunk index 0..15
            uint4 vr = *(const uint4*)((const char*)houtbase + (size_t)r * 512 + c16 * 16);
            *(uint4*)&featsB[e][c16 * 8] = vr;
            uint4 vc = *(const uint4*)((const char*)houtbase + (size_t)c * 512 + c16 * 16);
            *(uint4*)&featsB[e][FIN + c16 * 8] = vc;
        }
        if (q == 0) {
            rowlds[e] = r;
            const float cix = coord[(size_t)r*3+0], ciy = coord[(size_t)r*3+1], ciz = coord[(size_t)r*3+2];
            const float ckx = coord[(size_t)c*3+0], cky = coord[(size_t)c*3+1], ckz = coord[(size_t)c*3+2];
            const float dx = cix-ckx, dy = ciy-cky, dz = ciz-ckz;
            cdiff[e][0]=dx; cdiff[e][1]=dy; cdiff[e][2]=dz;
            const float radial = dx*dx + dy*dy + dz*dz;
            const float dist   = sqrtf(radial);
            const float dotv   = cix*ckx + ciy*cky + ciz*ckz;
            const float ia = 1.0f / (dist + 1e-8f);
            float ax = dx*ia, ay = dy*ia, az = dz*ia;
            const float cpx = ciy*ckz - ciz*cky;
            const float cpy = ciz*ckx - cix*ckz;
            const float cpz = cix*cky - ciy*ckx;
            const float cpn = sqrtf(cpx*cpx + cpy*cpy + cpz*cpz);
            const float ib = 1.0f / (cpn + 1e-8f);
            float bx = cpx*ib, by = cpy*ib, bz = cpz*ib;
            float cx = ay*bz - az*by;
            float cy = az*bx - ax*bz;
            float cz = ax*by - ay*bx;
            const float na = sqrtf(ax*ax + ay*ay + az*az);
            const float nb = sqrtf(bx*bx + by*by + bz*bz);
            const float nc = sqrtf(cx*cx + cy*cy + cz*cz);
            if (na < 1e-6f || nb < 1e-6f || nc < 1e-6f) {
                ax=1.f; bx=0.f; cx=0.f;
                ay=0.f; by=1.f; cy=0.f;
                az=0.f; bz=0.f; cz=1.f;
            }
            featsB[e][256]=(__bf16)radial; featsB[e][257]=(__bf16)dist; featsB[e][258]=(__bf16)dotv;
            featsB[e][259]=(__bf16)ax; featsB[e][260]=(__bf16)bx; featsB[e][261]=(__bf16)cx;
            featsB[e][262]=(__bf16)ay; featsB[e][263]=(__bf16)by; featsB[e][264]=(__bf16)cy;
            featsB[e][265]=(__bf16)az; featsB[e][266]=(__bf16)bz; featsB[e][267]=(__bf16)cz;
            #pragma unroll
            for (int k = FEATD; k < K1; k++) featsB[e][k] = (__bf16)0.f;
        }
    }
    __syncthreads();

    const int wv2  = t >> 6;          // wave 0..7
    const int hh   = wv2 >> 1;        // head (GEMM1/2) / col-group (GEMM3)
    const int mh   = wv2 & 1;         // edge-half: rows [mh*32, mh*32+32)
    const int lane = t & 63;
    const int lr   = lane & 15;       // fragment row/col index
    const int lg   = lane >> 4;       // k-group (0..3)

    __bf16* hidB = ((__bf16*)smemB) + hh * (TE * 40);

    const f32x4 z4 = { 0.f, 0.f, 0.f, 0.f };

    // ---------------- GEMM1 (MFMA): feats[64x288] @ eW1t^T -> hid per head ----------------
    {
        f32x4 acc[2][2];
        #pragma unroll
        for (int mti = 0; mti < 2; mti++) { acc[mti][0] = z4; acc[mti][1] = z4; }
        const __bf16* W1 = eW1t + (size_t)hh * 32 * K1;
        #pragma unroll
        for (int ks = 0; ks < 9; ks++) {
            const int kof = ks * 32 + lg * 8;
            bf16x8 b0 = *(const bf16x8*)(W1 + (size_t)lr * K1 + kof);
            bf16x8 b1 = *(const bf16x8*)(W1 + (size_t)(16 + lr) * K1 + kof);
            #pragma unroll
            for (int mti = 0; mti < 2; mti++) {
                bf16x8 a = *(const bf16x8*)(&featsB[(mh * 2 + mti) * 16 + lr][kof]);
                acc[mti][0] = MFMA(a, b0, acc[mti][0]);
                acc[mti][1] = MFMA(a, b1, acc[mti][1]);
            }
        }
        const float b1a = eb1[hh * HD + lr];
        const float b1b = eb1[hh * HD + 16 + lr];
        #pragma unroll
        for (int mti = 0; mti < 2; mti++) {
            #pragma unroll
            for (int r = 0; r < 4; r++) {
                const int erow = (mh * 2 + mti) * 16 + lg * 4 + r;
                hidB[erow * 40 + lr]      = (__bf16)silu_f(acc[mti][0][r] + b1a);
                hidB[erow * 40 + 16 + lr] = (__bf16)silu_f(acc[mti][1][r] + b1b);
            }
        }
    }
    __syncthreads();

    // ---------------- GEMM2 (MFMA): hid @ eW2t^T + b2 -> efs (fp32) ----------------
    {
        f32x4 acc2[2][2];
        #pragma unroll
        for (int mti = 0; mti < 2; mti++) { acc2[mti][0] = z4; acc2[mti][1] = z4; }
        const __bf16* W2 = eW2t + (size_t)hh * HD * HD;
        const int kof2 = lg * 8;
        bf16x8 b20 = *(const bf16x8*)(W2 + (size_t)lr * HD + kof2);
        bf16x8 b21 = *(const bf16x8*)(W2 + (size_t)(16 + lr) * HD + kof2);
        #pragma unroll
        for (int mti = 0; mti < 2; mti++) {
            bf16x8 a = *(const bf16x8*)(hidB + ((mh * 2 + mti) * 16 + lr) * 40 + kof2);
            acc2[mti][0] = MFMA(a, b20, acc2[mti][0]);
            acc2[mti][1] = MFMA(a, b21, acc2[mti][1]);
        }
        const float b2a = eb2[hh * HD + lr];
        const float b2b = eb2[hh * HD + 16 + lr];
        #pragma unroll
        for (int mti = 0; mti < 2; mti++) {
            #pragma unroll
            for (int r = 0; r < 4; r++) {
                const int erow = (mh * 2 + mti) * 16 + lg * 4 + r;
                efs[erow][hh * HD + lr]      = acc2[mti][0][r] + b2a;
                efs[erow][hh * HD + 16 + lr] = acc2[mti][1][r] + b2b;
            }
        }
    }
    __syncthreads();

    // ---------------- LayerNorm over 128 (8 threads/edge) ----------------
    {
        const int el = t >> 3;
        const int q8 = t & 7;
        float s = 0.f, s2 = 0.f;
        #pragma unroll
        for (int i = 0; i < 16; i++) {
            const float v = efs[el][q8 + 8 * i];
            s += v; s2 += v * v;
        }
        s  += __shfl_xor(s, 1);  s  += __shfl_xor(s, 2);  s  += __shfl_xor(s, 4);
        s2 += __shfl_xor(s2, 1); s2 += __shfl_xor(s2, 2); s2 += __shfl_xor(s2, 4);
        const float mu   = s * (1.f / 128.f);
        const float var  = s2 * (1.f / 128.f) - mu * mu;
        const float rstd = rsqrtf(var + 1e-5f);
        #pragma unroll
        for (int i = 0; i < 16; i++) {
            const int oo = q8 + 8 * i;
            const float v  = efs[el][oo];
            const float nv = (v - mu) * rstd * ln_g[oo] + ln_b[oo];
            efsB[el][oo] = (__bf16)nv;
        }
    }
    __syncthreads();

    // ---------------- GEMM3 (MFMA): efsB @ cW1t^T -> silu -> *cW2 -> w per edge ----------------
    {
        f32x4 acc3[2][2];
        #pragma unroll
        for (int mti = 0; mti < 2; mti++) { acc3[mti][0] = z4; acc3[mti][1] = z4; }
        const __bf16* W3 = cW1t + (size_t)hh * 32 * HIDN;
        #pragma unroll
        for (int ks = 0; ks < 4; ks++) {
            const int kof = ks * 32 + lg * 8;
            bf16x8 b30 = *(const bf16x8*)(W3 + (size_t)lr * HIDN + kof);
            bf16x8 b31 = *(const bf16x8*)(W3 + (size_t)(16 + lr) * HIDN + kof);
            #pragma unroll
            for (int mti = 0; mti < 2; mti++) {
                bf16x8 a = *(const bf16x8*)(&efsB[(mh * 2 + mti) * 16 + lr][kof]);
                acc3[mti][0] = MFMA(a, b30, acc3[mti][0]);
                acc3[mti][1] = MFMA(a, b31, acc3[mti][1]);
            }
        }
        const int c0 = hh * 32 + lr, c1 = c0 + 16;
        const float cbA = cb1[c0], cbB = cb1[c1];
        const float cwA = cW2[c0], cwB = cW2[c1];
        float pe[8];
        #pragma unroll
        for (int mti = 0; mti < 2; mti++)
            #pragma unroll
            for (int r = 0; r < 4; r++)
                pe[mti * 4 + r] = silu_f(acc3[mti][0][r] + cbA) * cwA
                                + silu_f(acc3[mti][1][r] + cbB) * cwB;
        #pragma unroll
        for (int d = 1; d < 16; d <<= 1)
            #pragma unroll
            for (int i = 0; i < 8; i++) pe[i] += __shfl_xor(pe[i], d);
        if (lr == 0) {
            #pragma unroll
            for (int mti = 0; mti < 2; mti++)
                #pragma unroll
                for (int r = 0; r < 4; r++)
                    atomicAdd(&wsum[(mh * 2 + mti) * 16 + lg * 4 + r], pe[mti * 4 + r]);
        }
    }
    __syncthreads();

    // ---------------- coord scatter ----------------
    if (t < TE) {
        const float we = wsum[t];
        const int r = rowlds[t];
        atomicAdd(&coord_out[(size_t)r*3+0], cdiff[t][0] * we);
        atomicAdd(&coord_out[(size_t)r*3+1], cdiff[t][1] * we);
        atomicAdd(&coord_out[(size_t)r*3+2], cdiff[t][2] * we);
    }

    // ---------------- agg scatter: packed 2xbf16 atomics straight from efsB ----------------
    {
        const int p  = t & 63;           // feature-pair index (0..63)
        const int gq = t >> 6;           // 0..7
        #pragma unroll
        for (int e2 = 0; e2 < 8; e2++) {
            const int ee = gq * 8 + e2;
            __hip_bfloat162 pk = *(__hip_bfloat162*)&efsB[ee][2 * p];   // stride-1, no cvt
            __hip_bfloat162* addr = (__hip_bfloat162*)
                ((char*)houtbase + (size_t)rowlds[ee] * 512 + 256 + p * 4);
            unsafeAtomicAdd(addr, pk);
        }
    }
}

// 512 threads = 8 waves. Reads the full 512B h_out row = [hB bf16[128] | agg bf16[128]]
// = the 256-dim bf16 node-MLP input, then overwrites the row with final f32 h_out.
__global__ __launch_bounds__(512) void node_kernel(
    const float* __restrict__ h,
    const __bf16* __restrict__ nW1t, const float* __restrict__ nb1,
    const __bf16* __restrict__ nW2t, const float* __restrict__ nb2,
    float* __restrict__ h_out)
{
    __shared__ __align__(16) __bf16 featsN[TN2][264];   // [64][256+8]
    __shared__ __align__(16) __bf16 hidN[TN2][136];     // [64][128+8]

    const int t  = threadIdx.x;
    const int n0 = blockIdx.x * TN2;

    // ---------------- Phase 0: stage [hB | agg] row directly ----------------
    {
        const int n = t >> 3;
        const int q = t & 7;
        const int nid = n0 + n;
        const bool ok = nid < NN;
        const uint4* rowp = (const uint4*)((const char*)h_out + (size_t)nid * 512);
        #pragma unroll
        for (int j = 0; j < 4; j++) {
            const int w4 = q * 4 + j;                  // uint4 index 0..31
            uint4 u = ok ? rowp[w4] : make_uint4(0u, 0u, 0u, 0u);
            *(uint4*)&featsN[n][w4 * 8] = u;
        }
    }
    __syncthreads();

    const int wv2  = t >> 6;
    const int hh2  = wv2 >> 1;        // output col-group (0..3)
    const int mh   = wv2 & 1;         // node-half
    const int lane = t & 63;
    const int lr   = lane & 15;
    const int lg   = lane >> 4;

    const f32x4 z4 = { 0.f, 0.f, 0.f, 0.f };

    // ---------------- GEMM1n (MFMA): featsN[64x256] @ nW1t^T -> silu -> hidN ----------------
    {
        f32x4 acc[2][2];
        #pragma unroll
        for (int mti = 0; mti < 2; mti++) { acc[mti][0] = z4; acc[mti][1] = z4; }
        const __bf16* W1 = nW1t + (size_t)hh2 * 32 * 256;
        #pragma unroll
        for (int ks = 0; ks < 8; ks++) {
            const int kof = ks * 32 + lg * 8;
            bf16x8 b0 = *(const bf16x8*)(W1 + (size_t)lr * 256 + kof);
            bf16x8 b1 = *(const bf16x8*)(W1 + (size_t)(16 + lr) * 256 + kof);
            #pragma unroll
            for (int mti = 0; mti < 2; mti++) {
                bf16x8 a = *(const bf16x8*)(&featsN[(mh * 2 + mti) * 16 + lr][kof]);
                acc[mti][0] = MFMA(a, b0, acc[mti][0]);
                acc[mti][1] = MFMA(a, b1, acc[mti][1]);
            }
        }
        const float b1a = nb1[hh2 * 32 + lr];
        const float b1b = nb1[hh2 * 32 + 16 + lr];
        #pragma unroll
        for (int mti = 0; mti < 2; mti++) {
            #pragma unroll
            for (int r = 0; r < 4; r++) {
                const int erow = (mh * 2 + mti) * 16 + lg * 4 + r;
                hidN[erow][hh2 * 32 + lr]      = (__bf16)silu_f(acc[mti][0][r] + b1a);
                hidN[erow][hh2 * 32 + 16 + lr] = (__bf16)silu_f(acc[mti][1][r] + b1b);
            }
        }
    }
    __syncthreads();

    // ---------------- GEMM2n (MFMA): hidN[64x128] @ nW2t^T + nb2 + h -> h_out ----------------
    {
        f32x4 acc2[2][2];
        #pragma unroll
        for (int mti = 0; mti < 2; mti++) { acc2[mti][0] = z4; acc2[mti][1] = z4; }
        const __bf16* W2 = nW2t + (size_t)hh2 * 32 * 128;
        #pragma unroll
        for (int ks = 0; ks < 4; ks++) {
            const int kof = ks * 32 + lg * 8;
            bf16x8 b0 = *(const bf16x8*)(W2 + (size_t)lr * 128 + kof);
            bf16x8 b1 = *(const bf16x8*)(W2 + (size_t)(16 + lr) * 128 + kof);
            #pragma unroll
            for (int mti = 0; mti < 2; mti++) {
                bf16x8 a = *(const bf16x8*)(&hidN[(mh * 2 + mti) * 16 + lr][kof]);
                acc2[mti][0] = MFMA(a, b0, acc2[mti][0]);
                acc2[mti][1] = MFMA(a, b1, acc2[mti][1]);
            }
        }
        const float b2a = nb2[hh2 * 32 + lr];
        const float b2b = nb2[hh2 * 32 + 16 + lr];
        const int c0 = hh2 * 32 + lr, c1 = c0 + 16;
        #pragma unroll
        for (int mti = 0; mti < 2; mti++) {
            #pragma unroll
            for (int r = 0; r < 4; r++) {
                const int erow = (mh * 2 + mti) * 16 + lg * 4 + r;
                const int nid  = n0 + erow;
                if (nid < NN) {
                    h_out[(size_t)nid * FIN + c0] = h[(size_t)nid * FIN + c0] + acc2[mti][0][r] + b2a;
                    h_out[(size_t)nid * FIN + c1] = h[(size_t)nid * FIN + c1] + acc2[mti][1][r] + b2b;
                }
            }
        }
    }
}

extern "C" void kernel_launch(void* const* d_in, const int* in_sizes, int n_in,
                              void* d_out, int out_size, void* d_ws, size_t ws_size,
                              hipStream_t stream)
{
    (void)in_sizes; (void)n_in; (void)out_size; (void)ws_size;
    const float* h     = (const float*)d_in[0];
    const float* coord = (const float*)d_in[1];
    const int*   ei    = (const int*)d_in[2];
    const float* eW1   = (const float*)d_in[3];
    const float* eb1   = (const float*)d_in[4];
    const float* eW2   = (const float*)d_in[5];
    const float* eb2   = (const float*)d_in[6];
    const float* ln_g  = (const float*)d_in[7];
    const float* ln_b  = (const float*)d_in[8];
    const float* nW1   = (const float*)d_in[9];
    const float* nb1   = (const float*)d_in[10];
    const float* nW2   = (const float*)d_in[11];
    const float* nb2   = (const float*)d_in[12];
    const float* cW1   = (const float*)d_in[13];
    const float* cb1   = (const float*)d_in[14];
    const float* cW2   = (const float*)d_in[15];

    float* h_out     = (float*)d_out;
    float* coord_out = h_out + (size_t)NN * FIN;

    // bf16 transposed weights in ws
    __bf16* eW1t = (__bf16*)d_ws;               // 36864 elems
    __bf16* eW2t = eW1t + 4 * 32 * K1;          // 4096
    __bf16* cW1t = eW2t + 4 * HD * HD;          // 16384
    __bf16* nW1t = cW1t + HIDN * HIDN;          // 32768
    __bf16* nW2t = nW1t + HIDN * (2 * FIN);     // 16384  (total ~213KB of ws)

    // h_out row layout during edge phase: [hB bf16[128] | packed-bf16 agg[128]]
    hipMemsetAsync(h_out, 0, (size_t)NN * FIN * sizeof(float), stream);
    hipMemcpyAsync(coord_out, coord, (size_t)NN * 3 * sizeof(float),
                   hipMemcpyDeviceToDevice, stream);
    wconv_kernel<<<(4 * 32 * K1 + 255) / 256, 256, 0, stream>>>(
        eW1, eW2, cW1, nW1, nW2, eW1t, eW2t, cW1t, nW1t, nW2t);
    hconv_kernel<<<(NN * FIN / 8 + 255) / 256, 256, 0, stream>>>(h, h_out);

    edge_kernel<<<EE / TE, 512, 0, stream>>>(coord, ei, eW1t, eb1, eW2t, eb2,
                                             ln_g, ln_b, cW1t, cb1, cW2,
                                             h_out, coord_out);
    node_kernel<<<(NN + TN2 - 1) / TN2, 512, 0, stream>>>(h, nW1t, nb1, nW2t, nb2, h_out);
}